// Round 6
// baseline (1270.727 us; speedup 1.0000x reference)
//
#include <hip/hip_runtime.h>
#include <hip/hip_bf16.h>
#include <cstdint>
#include <cstddef>

#define NFEAT 512
#define NHID1 256
#define NHID2 64
#define ATTH  16

typedef __attribute__((ext_vector_type(8))) short short8v;           // 8 bf16 (4 VGPRs)
typedef __attribute__((ext_vector_type(8))) unsigned short ushort8v; // 16B load
typedef __attribute__((ext_vector_type(4))) float f32x4;             // mfma accumulator

enum { EPI_NONE=0, EPI_RELU=1, EPI_BNRELU=2, EPI_SIGMOID=3, EPI_SOFTPLUS=4, EPI_EXPCLIP=5 };
enum { OUT_F32=0, OUT_BF16_ROW=1, OUT_BF16_SLICED=2 };

static __device__ __forceinline__ float bf2f(unsigned short u) {
    return __uint_as_float(((unsigned int)u) << 16);
}
static __device__ __forceinline__ unsigned short f2bf(float f) {
    __hip_bfloat16 h = __float2bfloat16(f);   // RNE
    return *reinterpret_cast<unsigned short*>(&h);
}

// ---------------- conversion kernels ----------------
__global__ __launch_bounds__(256) void convert_x_kernel(const float* __restrict__ in,
                                                        unsigned short* __restrict__ out, long n4) {
    long i = blockIdx.x * (long)blockDim.x + threadIdx.x;
    long stride = (long)gridDim.x * blockDim.x;
    for (; i < n4; i += stride) {
        float4 v = reinterpret_cast<const float4*>(in)[i];
        ushort4 o;
        o.x = f2bf(v.x); o.y = f2bf(v.y); o.z = f2bf(v.z); o.w = f2bf(v.w);
        reinterpret_cast<ushort4*>(out)[i] = o;
    }
}

struct WSpec { const float* W; unsigned short* Wt; int K, Nn; };
struct WPack { WSpec s[8]; };

// Wt[n][k] = bf16(W[k][n]) for all 8 weights in one launch; grid.y = weight id
__global__ __launch_bounds__(256) void convert_wt_all_kernel(WPack p) {
    WSpec sp = p.s[blockIdx.y];
    int total = sp.K * sp.Nn;
    for (int idx = blockIdx.x * 256 + threadIdx.x; idx < total; idx += gridDim.x * 256) {
        int n = idx / sp.K, k = idx % sp.K;
        sp.Wt[idx] = f2bf(sp.W[(size_t)k * sp.Nn + n]);
    }
}

// ---------------- bf16 MFMA GEMM: C = epi(A[M,K] @ Bt[Nn,K]^T + bias) ----------------
// 128x128 tile, 4 waves (2x2), 16x16x32 mfma, BK=32, global_load_lds width-16 staging.
// A_SLICED: A stored [K/32][M][32] slice-major. OUT_BF16_SLICED: C written [Nn/32][M][32].
template<int EPI, int OUT_MODE, int A_SLICED>
__global__ __launch_bounds__(256) void mfma_gemm_kernel(
    const unsigned short* __restrict__ A, const unsigned short* __restrict__ Bt,
    const float* __restrict__ bias, void* __restrict__ Cout,
    int M, int K, int Nn,
    const float* __restrict__ bn_g, const float* __restrict__ bn_b,
    const float* __restrict__ bn_m, const float* __restrict__ bn_v)
{
    __shared__ unsigned short As[128 * 32];
    __shared__ unsigned short Bs[128 * 32];
    const int t = threadIdx.x;
    const int w = t >> 6, l = t & 63;
    const int wr = w >> 1, wc = w & 1;
    const int rowBase = blockIdx.y * 128, colBase = blockIdx.x * 128;

    f32x4 acc[4][4];
    #pragma unroll
    for (int m = 0; m < 4; ++m)
        #pragma unroll
        for (int n = 0; n < 4; ++n) acc[m][n] = (f32x4){0.f, 0.f, 0.f, 0.f};

    const int c0 = w * 2, c1 = w * 2 + 1;
    const int r0 = c0 * 16 + (l >> 2), r1 = c1 * 16 + (l >> 2);
    const int kid = (l & 3) * 8;
    int ar0 = rowBase + r0; if (ar0 >= M) ar0 = M - 1;
    int ar1 = rowBase + r1; if (ar1 >= M) ar1 = M - 1;
    int br0 = colBase + r0; if (br0 >= Nn) br0 = Nn - 1;
    int br1 = colBase + r1; if (br1 >= Nn) br1 = Nn - 1;
    const unsigned short* a0p = A_SLICED ? (A + (size_t)ar0 * 32 + kid)
                                         : (A + (size_t)ar0 * K + kid);
    const unsigned short* a1p = A_SLICED ? (A + (size_t)ar1 * 32 + kid)
                                         : (A + (size_t)ar1 * K + kid);
    const unsigned short* b0p = Bt + (size_t)br0 * K + kid;
    const unsigned short* b1p = Bt + (size_t)br1 * K + kid;

    const int frow = (l & 15), fk = (l >> 4) * 8;

    for (int k0 = 0; k0 < K; k0 += 32) {
        const size_t aoff = A_SLICED ? (size_t)k0 * M : (size_t)k0;
        __builtin_amdgcn_global_load_lds(
            (const __attribute__((address_space(1))) void*)(a0p + aoff),
            (__attribute__((address_space(3))) void*)(As + c0 * 512), 16, 0, 0);
        __builtin_amdgcn_global_load_lds(
            (const __attribute__((address_space(1))) void*)(a1p + aoff),
            (__attribute__((address_space(3))) void*)(As + c1 * 512), 16, 0, 0);
        __builtin_amdgcn_global_load_lds(
            (const __attribute__((address_space(1))) void*)(b0p + k0),
            (__attribute__((address_space(3))) void*)(Bs + c0 * 512), 16, 0, 0);
        __builtin_amdgcn_global_load_lds(
            (const __attribute__((address_space(1))) void*)(b1p + k0),
            (__attribute__((address_space(3))) void*)(Bs + c1 * 512), 16, 0, 0);
        __syncthreads();

        short8v a[4], b[4];
        #pragma unroll
        for (int m = 0; m < 4; ++m)
            a[m] = *reinterpret_cast<const short8v*>(As + (wr * 64 + m * 16 + frow) * 32 + fk);
        #pragma unroll
        for (int n = 0; n < 4; ++n)
            b[n] = *reinterpret_cast<const short8v*>(Bs + (wc * 64 + n * 16 + frow) * 32 + fk);
        #pragma unroll
        for (int m = 0; m < 4; ++m)
            #pragma unroll
            for (int n = 0; n < 4; ++n)
                acc[m][n] = __builtin_amdgcn_mfma_f32_16x16x32_bf16(a[m], b[n], acc[m][n], 0, 0, 0);
        __syncthreads();
    }

    #pragma unroll
    for (int n = 0; n < 4; ++n) {
        int c = colBase + wc * 64 + n * 16 + (l & 15);
        if (c >= Nn) continue;
        float bia = bias ? bias[c] : 0.f;
        float g = 0.f, bb = 0.f, mm = 0.f, iv = 0.f;
        if (EPI == EPI_BNRELU) {
            g = bn_g[c]; bb = bn_b[c]; mm = bn_m[c];
            iv = rsqrtf(bn_v[c] + 1e-5f);
        }
        #pragma unroll
        for (int m = 0; m < 4; ++m) {
            #pragma unroll
            for (int j = 0; j < 4; ++j) {
                int r = rowBase + wr * 64 + m * 16 + (l >> 4) * 4 + j;
                if (r >= M) continue;
                float v = acc[m][n][j] + bia;
                if (EPI == EPI_RELU) {
                    v = fmaxf(v, 0.f);
                } else if (EPI == EPI_BNRELU) {
                    v = (v - mm) * iv * g + bb;
                    v = fmaxf(v, 0.f);
                } else if (EPI == EPI_SIGMOID) {
                    v = 1.f / (1.f + expf(-v));
                } else if (EPI == EPI_SOFTPLUS) {
                    float sp = (v > 20.f) ? v : log1pf(expf(v));
                    v = fminf(fmaxf(sp, 1e-4f), 1e4f);
                } else if (EPI == EPI_EXPCLIP) {
                    v = fminf(fmaxf(expf(v), 1e-5f), 1e6f);
                }
                if (OUT_MODE == OUT_BF16_SLICED)
                    ((unsigned short*)Cout)[((size_t)(c >> 5) * M + r) * 32 + (c & 31)] = f2bf(v);
                else if (OUT_MODE == OUT_BF16_ROW)
                    ((unsigned short*)Cout)[(size_t)r * Nn + c] = f2bf(v);
                else
                    ((float*)Cout)[(size_t)r * Nn + c] = v;
            }
        }
    }
}

// ---------------- combined CSR build (both graphs, rows 0..2N-1) ----------------
__global__ void hist2_kernel(const int* __restrict__ edst0, const int* __restrict__ edst1,
                             int* __restrict__ deg, int e, int nHalf) {
    int i = blockIdx.x * blockDim.x + threadIdx.x;
    if (i < 2 * e) {
        int d = (i < e) ? edst0[i] : (edst1[i - e] + nHalf);
        atomicAdd(&deg[d], 1);
    }
}

__global__ __launch_bounds__(1024) void scan_block_kernel(const int* __restrict__ deg,
                                                          int* __restrict__ excl,
                                                          int* __restrict__ bsum, int n) {
    __shared__ int buf[1024];
    int i = blockIdx.x * 1024 + (int)threadIdx.x;
    int v = (i < n) ? deg[i] : 0;
    buf[threadIdx.x] = v;
    __syncthreads();
    for (int off = 1; off < 1024; off <<= 1) {
        int tv = (threadIdx.x >= (unsigned)off) ? buf[threadIdx.x - off] : 0;
        __syncthreads();
        buf[threadIdx.x] += tv;
        __syncthreads();
    }
    if (i < n) excl[i] = buf[threadIdx.x] - v;
    if (threadIdx.x == 1023) bsum[blockIdx.x] = buf[1023];
}

__global__ __launch_bounds__(1024) void scan_tops_kernel(int* __restrict__ bsum, int nb) {
    __shared__ int buf[1024];
    int v = ((int)threadIdx.x < nb) ? bsum[threadIdx.x] : 0;
    buf[threadIdx.x] = v;
    __syncthreads();
    for (int off = 1; off < 1024; off <<= 1) {
        int tv = (threadIdx.x >= (unsigned)off) ? buf[threadIdx.x - off] : 0;
        __syncthreads();
        buf[threadIdx.x] += tv;
        __syncthreads();
    }
    if ((int)threadIdx.x < nb) bsum[threadIdx.x] = buf[threadIdx.x] - v;
}

__global__ void scan_add_kernel(int* __restrict__ row_start, const int* __restrict__ bsum,
                                const int* __restrict__ deg, int* __restrict__ cursor, int n) {
    int i = blockIdx.x * blockDim.x + threadIdx.x;
    if (i < n) {
        int s = row_start[i] + bsum[i >> 10];
        row_start[i] = s;
        cursor[i] = s;
        if (i == n - 1) row_start[n] = s + deg[i];
    }
}

// ---- windowed XCD-local scatter (unchanged) ----
#define SC_EPT 8
__global__ __launch_bounds__(256) void scatter_win_kernel(
    const int* __restrict__ sadj, const int* __restrict__ fadj,
    int* __restrict__ cursor, int* __restrict__ csr_src,
    int e, int nHalf, int winSize)
{
    const int win = blockIdx.x & 7;
    const int chunk = blockIdx.x >> 3;
    const int lo = win * winSize, hi = lo + winSize;
    const int base = chunk * (256 * SC_EPT);
    const int e2 = 2 * e;
    #pragma unroll
    for (int r = 0; r < SC_EPT; ++r) {
        int i = base + r * 256 + (int)threadIdx.x;
        if (i >= e2) break;
        int src, d;
        if (i < e) { src = sadj[i];     d = sadj[e + i]; }
        else       { int j = i - e; src = fadj[j]; d = fadj[e + j] + nHalf; }
        if (d >= lo && d < hi) {
            int pos = atomicAdd(&cursor[d], 1);
            csr_src[pos] = src;
        }
    }
}

// ---------------- per-slice gather aggregation (serialized launches) ----------------
// One launch per slice (and per half for layer 2) so the gather working set
// (one 3.2 MB slice region) is L2-resident per XCD. csr_src is streamed with
// nontemporal loads and the output with nontemporal stores to keep L2 clean.
// xsl: slice base [rows][32] bf16; outSl: [n2][32] for this slice.
// SELF_FOLD: self row = node - (node>=nHalf? nHalf:0) (layer 1, shared xw);
// else self = node (layer 2), with srcAdd selecting the half's row range.
template<bool SELF_FOLD>
__global__ __launch_bounds__(256) void agg_slice_kernel(
    const unsigned short* __restrict__ xsl, const int* __restrict__ row_start,
    const int* __restrict__ csr_src, const float* __restrict__ biasSl,
    unsigned short* __restrict__ outSl,
    int nodeBase, int nodeCnt, int srcAdd, int nHalf)
{
    const int rel = blockIdx.x * 64 + ((int)threadIdx.x >> 2);
    if (rel >= nodeCnt) return;
    const int node = nodeBase + rel;
    const int l4 = (int)threadIdx.x & 3;
    const unsigned short* base = xsl + l4 * 8;
    const int selfIdx = SELF_FOLD ? (node >= nHalf ? node - nHalf : node) : node;
    const int beg = row_start[node], end = row_start[node + 1];
    float a[8];
    #pragma unroll
    for (int j = 0; j < 8; ++j) a[j] = 0.f;
    int e = beg;
    for (; e + 4 <= end; e += 4) {
        int s0 = __builtin_nontemporal_load(csr_src + e)     + srcAdd;
        int s1 = __builtin_nontemporal_load(csr_src + e + 1) + srcAdd;
        int s2 = __builtin_nontemporal_load(csr_src + e + 2) + srcAdd;
        int s3 = __builtin_nontemporal_load(csr_src + e + 3) + srcAdd;
        ushort8v v0 = *reinterpret_cast<const ushort8v*>(base + (size_t)s0 * 32);
        ushort8v v1 = *reinterpret_cast<const ushort8v*>(base + (size_t)s1 * 32);
        ushort8v v2 = *reinterpret_cast<const ushort8v*>(base + (size_t)s2 * 32);
        ushort8v v3 = *reinterpret_cast<const ushort8v*>(base + (size_t)s3 * 32);
        #pragma unroll
        for (int j = 0; j < 8; ++j)
            a[j] += bf2f(v0[j]) + bf2f(v1[j]) + bf2f(v2[j]) + bf2f(v3[j]);
    }
    for (; e < end; ++e) {
        int si = __builtin_nontemporal_load(csr_src + e) + srcAdd;
        ushort8v v = *reinterpret_cast<const ushort8v*>(base + (size_t)si * 32);
        #pragma unroll
        for (int j = 0; j < 8; ++j) a[j] += bf2f(v[j]);
    }
    ushort8v sv = *reinterpret_cast<const ushort8v*>(base + (size_t)selfIdx * 32);
    ushort8v o;
    #pragma unroll
    for (int j = 0; j < 8; ++j)
        o[j] = f2bf(fmaxf(bf2f(sv[j]) + a[j] + biasSl[l4 * 8 + j], 0.f));
    __builtin_nontemporal_store(o,
        reinterpret_cast<ushort8v*>(outSl + (size_t)node * 32 + l4 * 8));
}

// ---------------- fused spatial attention + mlp (16 nodes/block) ----------------
__global__ __launch_bounds__(256) void attn_mlp_kernel(
    const float* __restrict__ emb1, const float* __restrict__ emb2,
    const float* __restrict__ Wa1, const float* __restrict__ ba1,
    const float* __restrict__ Wa2, const float* __restrict__ Wmlp,
    const float* __restrict__ bmlp, float* __restrict__ out,
    unsigned short* __restrict__ out_bf, int n)
{
    __shared__ float sWa1[NHID2][ATTH];
    __shared__ float sba1[ATTH], sWa2[ATTH];
    __shared__ float sWmlp[NHID2][NHID2 + 1];
    __shared__ float sbmlp[NHID2];
    __shared__ float zs[4][3][NHID2 + 1];
    __shared__ float part[4][3][ATTH];
    __shared__ float sbeta[4][3];
    __shared__ float es[4][NHID2 + 1];

    int t = threadIdx.x;
    for (int idx = t; idx < NHID2 * ATTH; idx += 256) sWa1[idx / ATTH][idx % ATTH] = Wa1[idx];
    if (t < ATTH) { sba1[t] = ba1[t]; sWa2[t] = Wa2[t]; }
    for (int idx = t; idx < NHID2 * NHID2; idx += 256) sWmlp[idx / NHID2][idx % NHID2] = Wmlp[idx];
    if (t < NHID2) sbmlp[t] = bmlp[t];

    int w = t >> 6, lane = t & 63;

    for (int rep = 0; rep < 4; ++rep) {
        int node = blockIdx.x * 16 + rep * 4 + w;
        float z0 = 0.f, z2 = 0.f;
        if (node < n) {
            z0 = emb1[(size_t)node * NHID2 + lane];
            z2 = emb2[(size_t)node * NHID2 + lane];
        }
        zs[w][0][lane] = z0;
        zs[w][1][lane] = 0.5f * (z0 + z2);
        zs[w][2][lane] = z2;
        __syncthreads();

        if (t < 192) {
            int ww = t / 48, k = (t / 16) % 3, h = t % 16;
            float p = 0.f;
            #pragma unroll 8
            for (int i = 0; i < NHID2; ++i) p += zs[ww][k][i] * sWa1[i][h];
            part[ww][k][h] = tanhf(p + sba1[h]) * sWa2[h];
        }
        __syncthreads();
        if (t < 12) {
            int ww = t / 3, k = t % 3;
            float s = 0.f;
            #pragma unroll
            for (int h = 0; h < ATTH; ++h) s += part[ww][k][h];
            part[ww][k][0] = s;
        }
        __syncthreads();
        if (t < 4) {
            float w0 = part[t][0][0], w1 = part[t][1][0], w2 = part[t][2][0];
            float m = fmaxf(w0, fmaxf(w1, w2));
            float e0 = expf(w0 - m), e1 = expf(w1 - m), e2 = expf(w2 - m);
            float d = e0 + e1 + e2;
            sbeta[t][0] = e0 / d; sbeta[t][1] = e1 / d; sbeta[t][2] = e2 / d;
        }
        __syncthreads();
        es[w][lane] = sbeta[w][0] * zs[w][0][lane] + sbeta[w][1] * zs[w][1][lane]
                    + sbeta[w][2] * zs[w][2][lane];
        __syncthreads();
        if (node < n) {
            float v = sbmlp[lane];
            #pragma unroll 8
            for (int i = 0; i < NHID2; ++i) v = fmaf(es[w][i], sWmlp[i][lane], v);
            out[(size_t)node * NHID2 + lane] = v;
            out_bf[(size_t)node * NHID2 + lane] = f2bf(v);
        }
        __syncthreads();
    }
}

// ---------------- launcher ----------------
extern "C" void kernel_launch(void* const* d_in, const int* in_sizes, int n_in,
                              void* d_out, int out_size, void* d_ws, size_t ws_size,
                              hipStream_t stream) {
    const float* x    = (const float*)d_in[0];
    const int*   sadj = (const int*)d_in[1];
    const int*   fadj = (const int*)d_in[2];
    const int N = in_sizes[0] / NFEAT;
    const int E = in_sizes[1] / 2;
    const int N2 = 2 * N;
    const float* Wg1a = (const float*)d_in[3];
    const float* bg1a = (const float*)d_in[4];
    const float* Wg1b = (const float*)d_in[5];
    const float* bg1b = (const float*)d_in[6];
    const float* Wg2a = (const float*)d_in[7];
    const float* bg2a = (const float*)d_in[8];
    const float* Wg2b = (const float*)d_in[9];
    const float* bg2b = (const float*)d_in[10];
    const float* Wa1  = (const float*)d_in[11];
    const float* ba1  = (const float*)d_in[12];
    const float* Wa2  = (const float*)d_in[13];
    const float* Wmlp = (const float*)d_in[14];
    const float* bmlp = (const float*)d_in[15];
    const float* Wd   = (const float*)d_in[16];
    const float* bd   = (const float*)d_in[17];
    const float* bn_g = (const float*)d_in[18];
    const float* bn_b = (const float*)d_in[19];
    const float* bn_m = (const float*)d_in[20];
    const float* bn_v = (const float*)d_in[21];
    const float* Wpi  = (const float*)d_in[22];
    const float* bpi  = (const float*)d_in[23];
    const float* Wv   = (const float*)d_in[24];
    const float* bv   = (const float*)d_in[25];
    const float* Wmu  = (const float*)d_in[26];
    const float* bmu  = (const float*)d_in[27];

    float* out   = (float*)d_out;
    float* emb1  = out;                              // [N,64] (emb2 follows)
    float* embO  = out + 2 * (size_t)N * NHID2;      // [N,64]
    float* pi    = out + 3 * (size_t)N * NHID2;      // [N,512]
    float* var_  = pi + (size_t)N * NFEAT;           // [N,512]
    float* mean_ = var_ + (size_t)N * NFEAT;         // [N,512]

    // ---- workspace carve (256B aligned) ----
    char* wsb = (char*)d_ws;
    auto alloc = [&](size_t bytes) { char* p = wsb; wsb += (bytes + 255) & ~(size_t)255; return p; };
    unsigned short* xw_sl   = (unsigned short*)alloc((size_t)N  * NHID1 * 2);  // [8][N][32]
    unsigned short* hw_sl   = (unsigned short*)alloc((size_t)N2 * NHID2 * 2);  // [2][N2][32]
    unsigned short* h3_sl   = (unsigned short*)alloc((size_t)N2 * NHID2 * 2);  // [2][N2][32]
    unsigned short* embO_bf = (unsigned short*)alloc((size_t)N  * NHID2 * 2);
    unsigned short* hdec_bf = (unsigned short*)alloc((size_t)N  * NHID1 * 2);
    unsigned short* Wg1a_t  = (unsigned short*)alloc((size_t)NFEAT * NHID1 * 2);
    unsigned short* Wg1b_t  = (unsigned short*)alloc((size_t)NHID1 * NHID1 * 2);
    unsigned short* Wg2a_t  = (unsigned short*)alloc((size_t)NHID1 * NHID2 * 2);
    unsigned short* Wg2b_t  = (unsigned short*)alloc((size_t)NHID2 * NHID2 * 2);
    unsigned short* Wd_t    = (unsigned short*)alloc((size_t)NHID2 * NHID1 * 2);
    unsigned short* Wpi_t   = (unsigned short*)alloc((size_t)NHID1 * NFEAT * 2);
    unsigned short* Wv_t    = (unsigned short*)alloc((size_t)NHID1 * NFEAT * 2);
    unsigned short* Wmu_t   = (unsigned short*)alloc((size_t)NHID1 * NFEAT * 2);
    int* deg       = (int*)alloc((size_t)N2 * 4);
    int* row_start = (int*)alloc((size_t)(N2 + 1) * 4);
    int* cursor    = (int*)alloc((size_t)N2 * 4);
    int* bsum      = (int*)alloc((size_t)1024 * 4);
    int* csr_src   = (int*)alloc((size_t)2 * E * 4);

    // big transient bf16 buffers live in not-yet-written output head segments
    unsigned short* x_bf  = (unsigned short*)mean_;  // [N,512]  bf16, row-major
    unsigned short* h1_sl = (unsigned short*)pi;     // [8][N2][32] bf16 slice-major
    unsigned short* h_bf  = (unsigned short*)var_;   // [2N,256] bf16, row-major

    const int gyN  = (N + 127) / 128;
    const int gyN2 = (N2 + 127) / 128;
    const int nb   = (N2 + 1023) / 1024;

    // ---- conversions ----
    convert_x_kernel<<<2048, 256, 0, stream>>>(x, x_bf, (long)N * NFEAT / 4);
    WPack wp;
    wp.s[0] = {Wg1a, Wg1a_t, NFEAT, NHID1};
    wp.s[1] = {Wg1b, Wg1b_t, NHID1, NHID1};
    wp.s[2] = {Wg2a, Wg2a_t, NHID1, NHID2};
    wp.s[3] = {Wg2b, Wg2b_t, NHID2, NHID2};
    wp.s[4] = {Wd,   Wd_t,   NHID2, NHID1};
    wp.s[5] = {Wpi,  Wpi_t,  NHID1, NFEAT};
    wp.s[6] = {Wv,   Wv_t,   NHID1, NFEAT};
    wp.s[7] = {Wmu,  Wmu_t,  NHID1, NFEAT};
    convert_wt_all_kernel<<<dim3(64, 8), 256, 0, stream>>>(wp);

    // ---- combined CSR build (both graphs) ----
    hipMemsetAsync(deg, 0, (size_t)N2 * sizeof(int), stream);
    hist2_kernel<<<(2 * E + 255) / 256, 256, 0, stream>>>(sadj + E, fadj + E, deg, E, N);
    scan_block_kernel<<<nb, 1024, 0, stream>>>(deg, row_start, bsum, N2);
    scan_tops_kernel<<<1, 1024, 0, stream>>>(bsum, nb);
    scan_add_kernel<<<(N2 + 255) / 256, 256, 0, stream>>>(row_start, bsum, deg, cursor, N2);
    {
        const int chunks = (2 * E + 256 * SC_EPT - 1) / (256 * SC_EPT);
        const int winSize = (N2 + 7) / 8;
        scatter_win_kernel<<<chunks * 8, 256, 0, stream>>>(
            sadj, fadj, cursor, csr_src, E, N, winSize);
    }

    // ---- GIN, both graphs batched as M = 2N ----
    // xw_sl = x @ Wg1a  (slice-major out)
    mfma_gemm_kernel<EPI_NONE, OUT_BF16_SLICED, 0><<<dim3(2, gyN), 256, 0, stream>>>(
        x_bf, Wg1a_t, nullptr, xw_sl, N, NFEAT, NHID1, nullptr, nullptr, nullptr, nullptr);
    // h1_sl = relu(xw_self + agg(xw) + bg1a)  — one launch per slice (L2-resident)
    for (int s = 0; s < NHID1 / 32; ++s) {
        agg_slice_kernel<true><<<(N2 + 63) / 64, 256, 0, stream>>>(
            xw_sl + (size_t)s * N * 32, row_start, csr_src, bg1a + s * 32,
            h1_sl + (size_t)s * N2 * 32, 0, N2, 0, N);
    }
    // h = relu(h1 @ Wg1b + bg1b)               [2N,256] row-major (A sliced)
    mfma_gemm_kernel<EPI_RELU, OUT_BF16_ROW, 1><<<dim3(2, gyN2), 256, 0, stream>>>(
        h1_sl, Wg1b_t, bg1b, h_bf, N2, NHID1, NHID1, nullptr, nullptr, nullptr, nullptr);
    // hw_sl = h @ Wg2a                         [2][2N][32]
    mfma_gemm_kernel<EPI_NONE, OUT_BF16_SLICED, 0><<<dim3(1, gyN2), 256, 0, stream>>>(
        h_bf, Wg2a_t, nullptr, hw_sl, N2, NHID1, NHID2, nullptr, nullptr, nullptr, nullptr);
    // h3_sl = relu(hw_self + agg(hw) + bg2a) — one launch per (slice, half)
    for (int s = 0; s < NHID2 / 32; ++s) {
        for (int h = 0; h < 2; ++h) {
            agg_slice_kernel<false><<<(N + 63) / 64, 256, 0, stream>>>(
                hw_sl + (size_t)s * N2 * 32, row_start, csr_src, bg2a + s * 32,
                h3_sl + (size_t)s * N2 * 32, h * N, N, h * N, N);
        }
    }
    // emb1‖emb2 = h3 @ Wg2b + bg2b  (fp32, contiguous in d_out; A sliced)
    mfma_gemm_kernel<EPI_NONE, OUT_F32, 1><<<dim3(1, gyN2), 256, 0, stream>>>(
        h3_sl, Wg2b_t, bg2b, emb1, N2, NHID2, NHID2, nullptr, nullptr, nullptr, nullptr);

    // ---- attention + mlp -> embO (fp32) + embO_bf ----
    attn_mlp_kernel<<<(N + 15) / 16, 256, 0, stream>>>(
        emb1, emb1 + (size_t)N * NHID2, Wa1, ba1, Wa2, Wmlp, bmlp, embO, embO_bf, N);

    // ---- decoder: hdec = relu(BN(embO @ Wd + bd)) ----
    mfma_gemm_kernel<EPI_BNRELU, OUT_BF16_ROW, 0><<<dim3(2, gyN), 256, 0, stream>>>(
        embO_bf, Wd_t, bd, hdec_bf, N, NHID2, NHID1, bn_g, bn_b, bn_m, bn_v);

    // ---- heads (fp32 final outputs) ----
    mfma_gemm_kernel<EPI_SIGMOID, OUT_F32, 0><<<dim3(4, gyN), 256, 0, stream>>>(
        hdec_bf, Wpi_t, bpi, pi, N, NHID1, NFEAT, nullptr, nullptr, nullptr, nullptr);
    mfma_gemm_kernel<EPI_SOFTPLUS, OUT_F32, 0><<<dim3(4, gyN), 256, 0, stream>>>(
        hdec_bf, Wv_t, bv, var_, N, NHID1, NFEAT, nullptr, nullptr, nullptr, nullptr);
    mfma_gemm_kernel<EPI_EXPCLIP, OUT_F32, 0><<<dim3(4, gyN), 256, 0, stream>>>(
        hdec_bf, Wmu_t, bmu, mean_, N, NHID1, NFEAT, nullptr, nullptr, nullptr, nullptr);
}

// Round 7
// 1075.739 us; speedup vs baseline: 1.1813x; 1.1813x over previous
//
#include <hip/hip_runtime.h>
#include <hip/hip_bf16.h>
#include <cstdint>
#include <cstddef>

#define NFEAT 512
#define NHID1 256
#define NHID2 64
#define ATTH  16

typedef __attribute__((ext_vector_type(8))) short short8v;           // 8 bf16 (4 VGPRs)
typedef __attribute__((ext_vector_type(8))) unsigned short ushort8v; // 16B load
typedef __attribute__((ext_vector_type(4))) float f32x4;             // mfma accumulator

enum { EPI_NONE=0, EPI_RELU=1, EPI_BNRELU=2, EPI_HEADS3=3 };

static __device__ __forceinline__ float bf2f(unsigned short u) {
    return __uint_as_float(((unsigned int)u) << 16);
}
static __device__ __forceinline__ unsigned short f2bf(float f) {
    __hip_bfloat16 h = __float2bfloat16(f);   // RNE
    return *reinterpret_cast<unsigned short*>(&h);
}

// ---------------- conversion kernels ----------------
__global__ __launch_bounds__(256) void convert_x_kernel(const float* __restrict__ in,
                                                        unsigned short* __restrict__ out, long n4) {
    long i = blockIdx.x * (long)blockDim.x + threadIdx.x;
    long stride = (long)gridDim.x * blockDim.x;
    for (; i < n4; i += stride) {
        float4 v = reinterpret_cast<const float4*>(in)[i];
        ushort4 o;
        o.x = f2bf(v.x); o.y = f2bf(v.y); o.z = f2bf(v.z); o.w = f2bf(v.w);
        reinterpret_cast<ushort4*>(out)[i] = o;
    }
}

struct WSpec { const float* W; unsigned short* Wt; int K, Nn; };
struct WPack { WSpec s[8]; };

// Wt[n][k] = bf16(W[k][n]) for all 8 weights in one launch; grid.y = weight id
__global__ __launch_bounds__(256) void convert_wt_all_kernel(WPack p) {
    WSpec sp = p.s[blockIdx.y];
    int total = sp.K * sp.Nn;
    for (int idx = blockIdx.x * 256 + threadIdx.x; idx < total; idx += gridDim.x * 256) {
        int n = idx / sp.K, k = idx % sp.K;
        sp.Wt[idx] = f2bf(sp.W[(size_t)k * sp.Nn + n]);
    }
}

// ---------------- bf16 MFMA GEMM: C = epi(A[M,K] @ Bt[Nn,K]^T + bias) ----------------
// 128x128 tile, 4 waves (2x2), 16x16x32 mfma, BK=32, global_load_lds width-16 staging.
// EPI_HEADS3: Nn=1536 = 3 heads x 512 cols; per-range activation; store to
// head segment h*headStride + r*512 + (c&511); biases via bp0/bp1/bp2.
template<int EPI, int OUT_BF16>
__global__ __launch_bounds__(256) void mfma_gemm_kernel(
    const unsigned short* __restrict__ A, const unsigned short* __restrict__ Bt,
    const float* __restrict__ bias, void* __restrict__ Cout,
    int M, int K, int Nn, long headStride,
    const float* __restrict__ bp0, const float* __restrict__ bp1,
    const float* __restrict__ bp2, const float* __restrict__ bp3)
{
    __shared__ unsigned short As[128 * 32];
    __shared__ unsigned short Bs[128 * 32];
    const int t = threadIdx.x;
    const int w = t >> 6, l = t & 63;
    const int wr = w >> 1, wc = w & 1;
    const int rowBase = blockIdx.y * 128, colBase = blockIdx.x * 128;

    f32x4 acc[4][4];
    #pragma unroll
    for (int m = 0; m < 4; ++m)
        #pragma unroll
        for (int n = 0; n < 4; ++n) acc[m][n] = (f32x4){0.f, 0.f, 0.f, 0.f};

    const int c0 = w * 2, c1 = w * 2 + 1;
    const int r0 = c0 * 16 + (l >> 2), r1 = c1 * 16 + (l >> 2);
    const int kid = (l & 3) * 8;
    int ar0 = rowBase + r0; if (ar0 >= M) ar0 = M - 1;
    int ar1 = rowBase + r1; if (ar1 >= M) ar1 = M - 1;
    int br0 = colBase + r0; if (br0 >= Nn) br0 = Nn - 1;
    int br1 = colBase + r1; if (br1 >= Nn) br1 = Nn - 1;
    const unsigned short* a0p = A + (size_t)ar0 * K + kid;
    const unsigned short* a1p = A + (size_t)ar1 * K + kid;
    const unsigned short* b0p = Bt + (size_t)br0 * K + kid;
    const unsigned short* b1p = Bt + (size_t)br1 * K + kid;

    const int frow = (l & 15), fk = (l >> 4) * 8;

    for (int k0 = 0; k0 < K; k0 += 32) {
        __builtin_amdgcn_global_load_lds(
            (const __attribute__((address_space(1))) void*)(a0p + k0),
            (__attribute__((address_space(3))) void*)(As + c0 * 512), 16, 0, 0);
        __builtin_amdgcn_global_load_lds(
            (const __attribute__((address_space(1))) void*)(a1p + k0),
            (__attribute__((address_space(3))) void*)(As + c1 * 512), 16, 0, 0);
        __builtin_amdgcn_global_load_lds(
            (const __attribute__((address_space(1))) void*)(b0p + k0),
            (__attribute__((address_space(3))) void*)(Bs + c0 * 512), 16, 0, 0);
        __builtin_amdgcn_global_load_lds(
            (const __attribute__((address_space(1))) void*)(b1p + k0),
            (__attribute__((address_space(3))) void*)(Bs + c1 * 512), 16, 0, 0);
        __syncthreads();

        short8v a[4], b[4];
        #pragma unroll
        for (int m = 0; m < 4; ++m)
            a[m] = *reinterpret_cast<const short8v*>(As + (wr * 64 + m * 16 + frow) * 32 + fk);
        #pragma unroll
        for (int n = 0; n < 4; ++n)
            b[n] = *reinterpret_cast<const short8v*>(Bs + (wc * 64 + n * 16 + frow) * 32 + fk);
        #pragma unroll
        for (int m = 0; m < 4; ++m)
            #pragma unroll
            for (int n = 0; n < 4; ++n)
                acc[m][n] = __builtin_amdgcn_mfma_f32_16x16x32_bf16(a[m], b[n], acc[m][n], 0, 0, 0);
        __syncthreads();
    }

    #pragma unroll
    for (int n = 0; n < 4; ++n) {
        int c = colBase + wc * 64 + n * 16 + (l & 15);
        if (c >= Nn) continue;
        float bia = 0.f, g = 0.f, bb = 0.f, mm = 0.f, iv = 0.f;
        int hh = 0, cc = c;
        if (EPI == EPI_HEADS3) {
            hh = c >> 9; cc = c & 511;
            bia = (hh == 0) ? bp0[cc] : (hh == 1) ? bp1[cc] : bp2[cc];
        } else {
            if (bias) bia = bias[c];
            if (EPI == EPI_BNRELU) {
                g = bp0[c]; bb = bp1[c]; mm = bp2[c];
                iv = rsqrtf(bp3[c] + 1e-5f);
            }
        }
        #pragma unroll
        for (int m = 0; m < 4; ++m) {
            #pragma unroll
            for (int j = 0; j < 4; ++j) {
                int r = rowBase + wr * 64 + m * 16 + (l >> 4) * 4 + j;
                if (r >= M) continue;
                float v = acc[m][n][j] + bia;
                if (EPI == EPI_RELU) {
                    v = fmaxf(v, 0.f);
                } else if (EPI == EPI_BNRELU) {
                    v = (v - mm) * iv * g + bb;
                    v = fmaxf(v, 0.f);
                } else if (EPI == EPI_HEADS3) {
                    if (hh == 0) {
                        v = 1.f / (1.f + expf(-v));
                    } else if (hh == 1) {
                        float sp = (v > 20.f) ? v : log1pf(expf(v));
                        v = fminf(fmaxf(sp, 1e-4f), 1e4f);
                    } else {
                        v = fminf(fmaxf(expf(v), 1e-5f), 1e6f);
                    }
                }
                if (EPI == EPI_HEADS3)
                    ((float*)Cout)[(size_t)hh * headStride + (size_t)r * 512 + cc] = v;
                else if (OUT_BF16)
                    ((unsigned short*)Cout)[(size_t)r * Nn + c] = f2bf(v);
                else
                    ((float*)Cout)[(size_t)r * Nn + c] = v;
            }
        }
    }
}

// ---------------- combined CSR build (both graphs, rows 0..2N-1) ----------------
__global__ void hist2_kernel(const int* __restrict__ edst0, const int* __restrict__ edst1,
                             int* __restrict__ deg, int e, int nHalf) {
    int i = blockIdx.x * blockDim.x + threadIdx.x;
    if (i < 2 * e) {
        int d = (i < e) ? edst0[i] : (edst1[i - e] + nHalf);
        atomicAdd(&deg[d], 1);
    }
}

__global__ __launch_bounds__(1024) void scan_block_kernel(const int* __restrict__ deg,
                                                          int* __restrict__ excl,
                                                          int* __restrict__ bsum, int n) {
    __shared__ int buf[1024];
    int i = blockIdx.x * 1024 + (int)threadIdx.x;
    int v = (i < n) ? deg[i] : 0;
    buf[threadIdx.x] = v;
    __syncthreads();
    for (int off = 1; off < 1024; off <<= 1) {
        int tv = (threadIdx.x >= (unsigned)off) ? buf[threadIdx.x - off] : 0;
        __syncthreads();
        buf[threadIdx.x] += tv;
        __syncthreads();
    }
    if (i < n) excl[i] = buf[threadIdx.x] - v;
    if (threadIdx.x == 1023) bsum[blockIdx.x] = buf[1023];
}

__global__ __launch_bounds__(1024) void scan_tops_kernel(int* __restrict__ bsum, int nb) {
    __shared__ int buf[1024];
    int v = ((int)threadIdx.x < nb) ? bsum[threadIdx.x] : 0;
    buf[threadIdx.x] = v;
    __syncthreads();
    for (int off = 1; off < 1024; off <<= 1) {
        int tv = (threadIdx.x >= (unsigned)off) ? buf[threadIdx.x - off] : 0;
        __syncthreads();
        buf[threadIdx.x] += tv;
        __syncthreads();
    }
    if ((int)threadIdx.x < nb) bsum[threadIdx.x] = buf[threadIdx.x] - v;
}

__global__ void scan_add_kernel(int* __restrict__ row_start, const int* __restrict__ bsum,
                                const int* __restrict__ deg, int* __restrict__ cursor, int n) {
    int i = blockIdx.x * blockDim.x + threadIdx.x;
    if (i < n) {
        int s = row_start[i] + bsum[i >> 10];
        row_start[i] = s;
        cursor[i] = s;
        if (i == n - 1) row_start[n] = s + deg[i];
    }
}

// ---- windowed XCD-local scatter ----
#define SC_EPT 8
__global__ __launch_bounds__(256) void scatter_win_kernel(
    const int* __restrict__ sadj, const int* __restrict__ fadj,
    int* __restrict__ cursor, int* __restrict__ csr_src,
    int e, int nHalf, int winSize)
{
    const int win = blockIdx.x & 7;
    const int chunk = blockIdx.x >> 3;
    const int lo = win * winSize, hi = lo + winSize;
    const int base = chunk * (256 * SC_EPT);
    const int e2 = 2 * e;
    #pragma unroll
    for (int r = 0; r < SC_EPT; ++r) {
        int i = base + r * 256 + (int)threadIdx.x;
        if (i >= e2) break;
        int src, d;
        if (i < e) { src = sadj[i];     d = sadj[e + i]; }
        else       { int j = i - e; src = fadj[j]; d = fadj[e + j] + nHalf; }
        if (d >= lo && d < hi) {
            int pos = atomicAdd(&cursor[d], 1);
            csr_src[pos] = src;
        }
    }
}

// ---------------- gather aggregation (bf16 rows, fp32 accum) — round-4 form ----------------
template<int F, bool SRC_OFFSET>
__global__ __launch_bounds__(256) void agg_combine_kernel(
    const unsigned short* __restrict__ xin, const int* __restrict__ row_start,
    const int* __restrict__ csr_src, const float* __restrict__ bias,
    unsigned short* __restrict__ out, int n2, int nHalf)
{
    constexpr int LPN = F / 8;                 // lanes per node, 8 bf16 (16B) each
    int node = blockIdx.x * (256 / LPN) + (int)threadIdx.x / LPN;
    int lane = (int)threadIdx.x % LPN;
    if (node >= n2) return;
    const int srcAdd  = (SRC_OFFSET && node >= nHalf) ? nHalf : 0;
    const int selfIdx = SRC_OFFSET ? node : (node >= nHalf ? node - nHalf : node);
    int beg = row_start[node], end = row_start[node + 1];
    float a[8];
    #pragma unroll
    for (int j = 0; j < 8; ++j) a[j] = 0.f;
    int e = beg;
    for (; e + 4 <= end; e += 4) {
        int s0 = csr_src[e] + srcAdd, s1 = csr_src[e+1] + srcAdd;
        int s2 = csr_src[e+2] + srcAdd, s3 = csr_src[e+3] + srcAdd;
        ushort8v v0 = *reinterpret_cast<const ushort8v*>(xin + (size_t)s0 * F + lane * 8);
        ushort8v v1 = *reinterpret_cast<const ushort8v*>(xin + (size_t)s1 * F + lane * 8);
        ushort8v v2 = *reinterpret_cast<const ushort8v*>(xin + (size_t)s2 * F + lane * 8);
        ushort8v v3 = *reinterpret_cast<const ushort8v*>(xin + (size_t)s3 * F + lane * 8);
        #pragma unroll
        for (int j = 0; j < 8; ++j)
            a[j] += bf2f(v0[j]) + bf2f(v1[j]) + bf2f(v2[j]) + bf2f(v3[j]);
    }
    for (; e < end; ++e) {
        int s = csr_src[e] + srcAdd;
        ushort8v v = *reinterpret_cast<const ushort8v*>(xin + (size_t)s * F + lane * 8);
        #pragma unroll
        for (int j = 0; j < 8; ++j) a[j] += bf2f(v[j]);
    }
    ushort8v sv = *reinterpret_cast<const ushort8v*>(xin + (size_t)selfIdx * F + lane * 8);
    ushort8v o;
    #pragma unroll
    for (int j = 0; j < 8; ++j)
        o[j] = f2bf(fmaxf(bf2f(sv[j]) + a[j] + bias[lane * 8 + j], 0.f));
    *reinterpret_cast<ushort8v*>(out + (size_t)node * F + lane * 8) = o;
}

// ---------------- fused spatial attention + mlp (16 nodes/block) ----------------
__global__ __launch_bounds__(256) void attn_mlp_kernel(
    const float* __restrict__ emb1, const float* __restrict__ emb2,
    const float* __restrict__ Wa1, const float* __restrict__ ba1,
    const float* __restrict__ Wa2, const float* __restrict__ Wmlp,
    const float* __restrict__ bmlp, float* __restrict__ out,
    unsigned short* __restrict__ out_bf, int n)
{
    __shared__ float sWa1[NHID2][ATTH];
    __shared__ float sba1[ATTH], sWa2[ATTH];
    __shared__ float sWmlp[NHID2][NHID2 + 1];
    __shared__ float sbmlp[NHID2];
    __shared__ float zs[4][3][NHID2 + 1];
    __shared__ float part[4][3][ATTH];
    __shared__ float sbeta[4][3];
    __shared__ float es[4][NHID2 + 1];

    int t = threadIdx.x;
    for (int idx = t; idx < NHID2 * ATTH; idx += 256) sWa1[idx / ATTH][idx % ATTH] = Wa1[idx];
    if (t < ATTH) { sba1[t] = ba1[t]; sWa2[t] = Wa2[t]; }
    for (int idx = t; idx < NHID2 * NHID2; idx += 256) sWmlp[idx / NHID2][idx % NHID2] = Wmlp[idx];
    if (t < NHID2) sbmlp[t] = bmlp[t];

    int w = t >> 6, lane = t & 63;

    for (int rep = 0; rep < 4; ++rep) {
        int node = blockIdx.x * 16 + rep * 4 + w;
        float z0 = 0.f, z2 = 0.f;
        if (node < n) {
            z0 = emb1[(size_t)node * NHID2 + lane];
            z2 = emb2[(size_t)node * NHID2 + lane];
        }
        zs[w][0][lane] = z0;
        zs[w][1][lane] = 0.5f * (z0 + z2);
        zs[w][2][lane] = z2;
        __syncthreads();

        if (t < 192) {
            int ww = t / 48, k = (t / 16) % 3, h = t % 16;
            float p = 0.f;
            #pragma unroll 8
            for (int i = 0; i < NHID2; ++i) p += zs[ww][k][i] * sWa1[i][h];
            part[ww][k][h] = tanhf(p + sba1[h]) * sWa2[h];
        }
        __syncthreads();
        if (t < 12) {
            int ww = t / 3, k = t % 3;
            float s = 0.f;
            #pragma unroll
            for (int h = 0; h < ATTH; ++h) s += part[ww][k][h];
            part[ww][k][0] = s;
        }
        __syncthreads();
        if (t < 4) {
            float w0 = part[t][0][0], w1 = part[t][1][0], w2 = part[t][2][0];
            float m = fmaxf(w0, fmaxf(w1, w2));
            float e0 = expf(w0 - m), e1 = expf(w1 - m), e2 = expf(w2 - m);
            float d = e0 + e1 + e2;
            sbeta[t][0] = e0 / d; sbeta[t][1] = e1 / d; sbeta[t][2] = e2 / d;
        }
        __syncthreads();
        es[w][lane] = sbeta[w][0] * zs[w][0][lane] + sbeta[w][1] * zs[w][1][lane]
                    + sbeta[w][2] * zs[w][2][lane];
        __syncthreads();
        if (node < n) {
            float v = sbmlp[lane];
            #pragma unroll 8
            for (int i = 0; i < NHID2; ++i) v = fmaf(es[w][i], sWmlp[i][lane], v);
            out[(size_t)node * NHID2 + lane] = v;
            out_bf[(size_t)node * NHID2 + lane] = f2bf(v);
        }
        __syncthreads();
    }
}

// ---------------- launcher ----------------
extern "C" void kernel_launch(void* const* d_in, const int* in_sizes, int n_in,
                              void* d_out, int out_size, void* d_ws, size_t ws_size,
                              hipStream_t stream) {
    const float* x    = (const float*)d_in[0];
    const int*   sadj = (const int*)d_in[1];
    const int*   fadj = (const int*)d_in[2];
    const int N = in_sizes[0] / NFEAT;
    const int E = in_sizes[1] / 2;
    const int N2 = 2 * N;
    const float* Wg1a = (const float*)d_in[3];
    const float* bg1a = (const float*)d_in[4];
    const float* Wg1b = (const float*)d_in[5];
    const float* bg1b = (const float*)d_in[6];
    const float* Wg2a = (const float*)d_in[7];
    const float* bg2a = (const float*)d_in[8];
    const float* Wg2b = (const float*)d_in[9];
    const float* bg2b = (const float*)d_in[10];
    const float* Wa1  = (const float*)d_in[11];
    const float* ba1  = (const float*)d_in[12];
    const float* Wa2  = (const float*)d_in[13];
    const float* Wmlp = (const float*)d_in[14];
    const float* bmlp = (const float*)d_in[15];
    const float* Wd   = (const float*)d_in[16];
    const float* bd   = (const float*)d_in[17];
    const float* bn_g = (const float*)d_in[18];
    const float* bn_b = (const float*)d_in[19];
    const float* bn_m = (const float*)d_in[20];
    const float* bn_v = (const float*)d_in[21];
    const float* Wpi  = (const float*)d_in[22];
    const float* bpi  = (const float*)d_in[23];
    const float* Wv   = (const float*)d_in[24];
    const float* bv   = (const float*)d_in[25];
    const float* Wmu  = (const float*)d_in[26];
    const float* bmu  = (const float*)d_in[27];

    float* out   = (float*)d_out;
    float* emb1  = out;                              // [N,64] (emb2 follows)
    float* embO  = out + 2 * (size_t)N * NHID2;      // [N,64]
    float* pi    = out + 3 * (size_t)N * NHID2;      // [N,512]
    float* var_  = pi + (size_t)N * NFEAT;           // [N,512]
    float* mean_ = var_ + (size_t)N * NFEAT;         // [N,512]

    // ---- workspace carve (256B aligned) ----
    char* wsb = (char*)d_ws;
    auto alloc = [&](size_t bytes) { char* p = wsb; wsb += (bytes + 255) & ~(size_t)255; return p; };
    unsigned short* xw_bf   = (unsigned short*)alloc((size_t)N  * NHID1 * 2);
    unsigned short* hw_bf   = (unsigned short*)alloc((size_t)N2 * NHID2 * 2);
    unsigned short* h3_bf   = (unsigned short*)alloc((size_t)N2 * NHID2 * 2);
    unsigned short* embO_bf = (unsigned short*)alloc((size_t)N  * NHID2 * 2);
    unsigned short* hdec_bf = (unsigned short*)alloc((size_t)N  * NHID1 * 2);
    unsigned short* Wg1a_t  = (unsigned short*)alloc((size_t)NFEAT * NHID1 * 2);
    unsigned short* Wg1b_t  = (unsigned short*)alloc((size_t)NHID1 * NHID1 * 2);
    unsigned short* Wg2a_t  = (unsigned short*)alloc((size_t)NHID1 * NHID2 * 2);
    unsigned short* Wg2b_t  = (unsigned short*)alloc((size_t)NHID2 * NHID2 * 2);
    unsigned short* Wd_t    = (unsigned short*)alloc((size_t)NHID2 * NHID1 * 2);
    unsigned short* Wcat_t  = (unsigned short*)alloc((size_t)3 * NFEAT * NHID1 * 2); // [1536][256]
    int* deg       = (int*)alloc((size_t)N2 * 4);
    int* row_start = (int*)alloc((size_t)(N2 + 1) * 4);
    int* cursor    = (int*)alloc((size_t)N2 * 4);
    int* bsum      = (int*)alloc((size_t)1024 * 4);
    int* csr_src   = (int*)alloc((size_t)2 * E * 4);

    // big transient bf16 buffers live in not-yet-written output head segments
    unsigned short* x_bf  = (unsigned short*)mean_;  // [N,512]  bf16
    unsigned short* h1_bf = (unsigned short*)pi;     // [2N,256] bf16
    unsigned short* h_bf  = (unsigned short*)var_;   // [2N,256] bf16

    const int gyN  = (N + 127) / 128;
    const int gyN2 = (N2 + 127) / 128;
    const int nb   = (N2 + 1023) / 1024;

    // ---- conversions ----
    convert_x_kernel<<<2048, 256, 0, stream>>>(x, x_bf, (long)N * NFEAT / 4);
    WPack wp;
    wp.s[0] = {Wg1a, Wg1a_t, NFEAT, NHID1};
    wp.s[1] = {Wg1b, Wg1b_t, NHID1, NHID1};
    wp.s[2] = {Wg2a, Wg2a_t, NHID1, NHID2};
    wp.s[3] = {Wg2b, Wg2b_t, NHID2, NHID2};
    wp.s[4] = {Wd,   Wd_t,   NHID2, NHID1};
    wp.s[5] = {Wpi,  Wcat_t,                          NHID1, NFEAT};
    wp.s[6] = {Wv,   Wcat_t + (size_t)NFEAT * NHID1,  NHID1, NFEAT};
    wp.s[7] = {Wmu,  Wcat_t + (size_t)2 * NFEAT * NHID1, NHID1, NFEAT};
    convert_wt_all_kernel<<<dim3(64, 8), 256, 0, stream>>>(wp);

    // ---- combined CSR build (both graphs) ----
    hipMemsetAsync(deg, 0, (size_t)N2 * sizeof(int), stream);
    hist2_kernel<<<(2 * E + 255) / 256, 256, 0, stream>>>(sadj + E, fadj + E, deg, E, N);
    scan_block_kernel<<<nb, 1024, 0, stream>>>(deg, row_start, bsum, N2);
    scan_tops_kernel<<<1, 1024, 0, stream>>>(bsum, nb);
    scan_add_kernel<<<(N2 + 255) / 256, 256, 0, stream>>>(row_start, bsum, deg, cursor, N2);
    {
        const int chunks = (2 * E + 256 * SC_EPT - 1) / (256 * SC_EPT);
        const int winSize = (N2 + 7) / 8;
        scatter_win_kernel<<<chunks * 8, 256, 0, stream>>>(
            sadj, fadj, cursor, csr_src, E, N, winSize);
    }

    // ---- GIN, both graphs batched as M = 2N ----
    // xw = x @ Wg1a
    mfma_gemm_kernel<EPI_NONE,1><<<dim3(2, gyN), 256, 0, stream>>>(
        x_bf, Wg1a_t, nullptr, xw_bf, N, NFEAT, NHID1, 0,
        nullptr, nullptr, nullptr, nullptr);
    // h1 = relu(xw_self + agg(xw) + bg1a)   [2N,256]
    agg_combine_kernel<NHID1,false><<<(N2 * (NHID1/8) + 255) / 256, 256, 0, stream>>>(
        xw_bf, row_start, csr_src, bg1a, h1_bf, N2, N);
    // h = relu(h1 @ Wg1b + bg1b)            [2N,256]
    mfma_gemm_kernel<EPI_RELU,1><<<dim3(2, gyN2), 256, 0, stream>>>(
        h1_bf, Wg1b_t, bg1b, h_bf, N2, NHID1, NHID1, 0,
        nullptr, nullptr, nullptr, nullptr);
    // hw = h @ Wg2a                         [2N,64]
    mfma_gemm_kernel<EPI_NONE,1><<<dim3(1, gyN2), 256, 0, stream>>>(
        h_bf, Wg2a_t, nullptr, hw_bf, N2, NHID1, NHID2, 0,
        nullptr, nullptr, nullptr, nullptr);
    // h3 = relu(hw_self + agg(hw) + bg2a)   [2N,64]
    agg_combine_kernel<NHID2,true><<<(N2 * (NHID2/8) + 255) / 256, 256, 0, stream>>>(
        hw_bf, row_start, csr_src, bg2a, h3_bf, N2, N);
    // emb1‖emb2 = h3 @ Wg2b + bg2b  (fp32, contiguous in d_out)
    mfma_gemm_kernel<EPI_NONE,0><<<dim3(1, gyN2), 256, 0, stream>>>(
        h3_bf, Wg2b_t, bg2b, emb1, N2, NHID2, NHID2, 0,
        nullptr, nullptr, nullptr, nullptr);

    // ---- attention + mlp -> embO (fp32) + embO_bf ----
    attn_mlp_kernel<<<(N + 15) / 16, 256, 0, stream>>>(
        emb1, emb1 + (size_t)N * NHID2, Wa1, ba1, Wa2, Wmlp, bmlp, embO, embO_bf, N);

    // ---- decoder: hdec = relu(BN(embO @ Wd + bd)) ----
    mfma_gemm_kernel<EPI_BNRELU,1><<<dim3(2, gyN), 256, 0, stream>>>(
        embO_bf, Wd_t, bd, hdec_bf, N, NHID2, NHID1, 0,
        bn_g, bn_b, bn_m, bn_v);

    // ---- fused heads: [pi | var | mean] = acts(hdec @ [Wpi|Wv|Wmu]^T + b) ----
    mfma_gemm_kernel<EPI_HEADS3,0><<<dim3(12, gyN), 256, 0, stream>>>(
        hdec_bf, Wcat_t, nullptr, pi, N, NHID1, 3 * NFEAT, (long)N * NFEAT,
        bpi, bv, bmu, nullptr);
}

// Round 8
// 883.405 us; speedup vs baseline: 1.4384x; 1.2177x over previous
//
#include <hip/hip_runtime.h>
#include <hip/hip_bf16.h>
#include <cstdint>
#include <cstddef>

#define NFEAT 512
#define NHID1 256
#define NHID2 64
#define ATTH  16

typedef __attribute__((ext_vector_type(8))) short short8v;           // 8 bf16 (4 VGPRs)
typedef __attribute__((ext_vector_type(8))) unsigned short ushort8v; // 16B load
typedef __attribute__((ext_vector_type(4))) float f32x4;             // mfma accumulator

enum { EPI_NONE=0, EPI_RELU=1, EPI_BNRELU=2, EPI_HEADS3=3 };

static __device__ __forceinline__ float bf2f(unsigned short u) {
    return __uint_as_float(((unsigned int)u) << 16);
}
static __device__ __forceinline__ unsigned short f2bf(float f) {
    __hip_bfloat16 h = __float2bfloat16(f);   // RNE
    return *reinterpret_cast<unsigned short*>(&h);
}

// ---------------- conversion kernels ----------------
__global__ __launch_bounds__(256) void convert_x_kernel(const float* __restrict__ in,
                                                        unsigned short* __restrict__ out, long n4) {
    long i = blockIdx.x * (long)blockDim.x + threadIdx.x;
    long stride = (long)gridDim.x * blockDim.x;
    for (; i < n4; i += stride) {
        float4 v = reinterpret_cast<const float4*>(in)[i];
        ushort4 o;
        o.x = f2bf(v.x); o.y = f2bf(v.y); o.z = f2bf(v.z); o.w = f2bf(v.w);
        reinterpret_cast<ushort4*>(out)[i] = o;
    }
}

struct WSpec { const float* W; unsigned short* Wt; int K, Nn; };
struct WPack { WSpec s[8]; };

// Wt[n][k] = bf16(W[k][n]) for all 8 weights in one launch; grid.y = weight id
__global__ __launch_bounds__(256) void convert_wt_all_kernel(WPack p) {
    WSpec sp = p.s[blockIdx.y];
    int total = sp.K * sp.Nn;
    for (int idx = blockIdx.x * 256 + threadIdx.x; idx < total; idx += gridDim.x * 256) {
        int n = idx / sp.K, k = idx % sp.K;
        sp.Wt[idx] = f2bf(sp.W[(size_t)k * sp.Nn + n]);
    }
}

// ---------------- bf16 MFMA GEMM: C = epi(A[M,K] @ Bt[Nn,K]^T + bias) ----------------
// 128x128 tile, 4 waves (2x2), 16x16x32 mfma, BK=32, global_load_lds width-16 staging.
// Epilogue: per m-quadrant LDS transpose (32 rows x 128 cols fp32, stride 132)
// -> vectorized row-major float4/ushort4 stores (full-line writes).
// EPI_HEADS3: Nn=1536 = 3 heads x 512 cols (block tile never straddles a head);
// per-head activation; store to hh*headStride + r*512 + (c&511).
template<int EPI, int OUT_BF16>
__global__ __launch_bounds__(256) void mfma_gemm_kernel(
    const unsigned short* __restrict__ A, const unsigned short* __restrict__ Bt,
    const float* __restrict__ bias, void* __restrict__ Cout,
    int M, int K, int Nn, long headStride,
    const float* __restrict__ bp0, const float* __restrict__ bp1,
    const float* __restrict__ bp2, const float* __restrict__ bp3)
{
    __shared__ __align__(16) char smem[32 * 132 * 4];   // 16896 B (>= 16384 staging)
    unsigned short* As = (unsigned short*)smem;         // 128*32 u16 = 8 KB
    unsigned short* Bs = As + 128 * 32;                 // 8 KB
    float* Es = (float*)smem;                           // epilogue transpose buffer

    const int t = threadIdx.x;
    const int w = t >> 6, l = t & 63;
    const int wr = w >> 1, wc = w & 1;
    const int rowBase = blockIdx.y * 128, colBase = blockIdx.x * 128;

    f32x4 acc[4][4];
    #pragma unroll
    for (int m = 0; m < 4; ++m)
        #pragma unroll
        for (int n = 0; n < 4; ++n) acc[m][n] = (f32x4){0.f, 0.f, 0.f, 0.f};

    const int c0 = w * 2, c1 = w * 2 + 1;
    const int r0 = c0 * 16 + (l >> 2), r1 = c1 * 16 + (l >> 2);
    const int kid = (l & 3) * 8;
    int ar0 = rowBase + r0; if (ar0 >= M) ar0 = M - 1;
    int ar1 = rowBase + r1; if (ar1 >= M) ar1 = M - 1;
    int br0 = colBase + r0; if (br0 >= Nn) br0 = Nn - 1;
    int br1 = colBase + r1; if (br1 >= Nn) br1 = Nn - 1;
    const unsigned short* a0p = A + (size_t)ar0 * K + kid;
    const unsigned short* a1p = A + (size_t)ar1 * K + kid;
    const unsigned short* b0p = Bt + (size_t)br0 * K + kid;
    const unsigned short* b1p = Bt + (size_t)br1 * K + kid;

    const int frow = (l & 15), fk = (l >> 4) * 8;

    for (int k0 = 0; k0 < K; k0 += 32) {
        __builtin_amdgcn_global_load_lds(
            (const __attribute__((address_space(1))) void*)(a0p + k0),
            (__attribute__((address_space(3))) void*)(As + c0 * 512), 16, 0, 0);
        __builtin_amdgcn_global_load_lds(
            (const __attribute__((address_space(1))) void*)(a1p + k0),
            (__attribute__((address_space(3))) void*)(As + c1 * 512), 16, 0, 0);
        __builtin_amdgcn_global_load_lds(
            (const __attribute__((address_space(1))) void*)(b0p + k0),
            (__attribute__((address_space(3))) void*)(Bs + c0 * 512), 16, 0, 0);
        __builtin_amdgcn_global_load_lds(
            (const __attribute__((address_space(1))) void*)(b1p + k0),
            (__attribute__((address_space(3))) void*)(Bs + c1 * 512), 16, 0, 0);
        __syncthreads();

        short8v a[4], b[4];
        #pragma unroll
        for (int m = 0; m < 4; ++m)
            a[m] = *reinterpret_cast<const short8v*>(As + (wr * 64 + m * 16 + frow) * 32 + fk);
        #pragma unroll
        for (int n = 0; n < 4; ++n)
            b[n] = *reinterpret_cast<const short8v*>(Bs + (wc * 64 + n * 16 + frow) * 32 + fk);
        #pragma unroll
        for (int m = 0; m < 4; ++m)
            #pragma unroll
            for (int n = 0; n < 4; ++n)
                acc[m][n] = __builtin_amdgcn_mfma_f32_16x16x32_bf16(a[m], b[n], acc[m][n], 0, 0, 0);
        __syncthreads();
    }

    // ---- epilogue: activation in fragment layout -> LDS -> vectorized stores ----
    const int colLoc = wc * 64 + (l & 15);        // + n*16
    const int lrBase = wr * 16 + (l >> 4) * 4;    // + j  (0..31)
    const int hh = colBase >> 9;                   // HEADS3: block-uniform head id
    const int ccBase = colBase & 511;

    #pragma unroll
    for (int m = 0; m < 4; ++m) {
        #pragma unroll
        for (int n = 0; n < 4; ++n) {
            const int cl = colLoc + n * 16;
            const int c  = colBase + cl;
            const int cs = (c < Nn) ? c : 0;      // safe index for OOB cols (Nn=64 tiles)
            float bia = 0.f, g = 0.f, bb = 0.f, mm = 0.f, iv = 0.f;
            if (EPI == EPI_HEADS3) {
                int cc = c & 511;
                bia = (hh == 0) ? bp0[cc] : (hh == 1) ? bp1[cc] : bp2[cc];
            } else {
                if (bias) bia = bias[cs];
                if (EPI == EPI_BNRELU) {
                    g = bp0[cs]; bb = bp1[cs]; mm = bp2[cs];
                    iv = rsqrtf(bp3[cs] + 1e-5f);
                }
            }
            #pragma unroll
            for (int j = 0; j < 4; ++j) {
                float v = acc[m][n][j] + bia;
                if (EPI == EPI_RELU) {
                    v = fmaxf(v, 0.f);
                } else if (EPI == EPI_BNRELU) {
                    v = (v - mm) * iv * g + bb;
                    v = fmaxf(v, 0.f);
                } else if (EPI == EPI_HEADS3) {
                    if (hh == 0) {
                        v = 1.f / (1.f + __expf(-v));
                    } else if (hh == 1) {
                        float sp = (v > 20.f) ? v : __logf(1.f + __expf(v));
                        v = fminf(fmaxf(sp, 1e-4f), 1e4f);
                    } else {
                        v = fminf(fmaxf(__expf(v), 1e-5f), 1e6f);
                    }
                }
                Es[(lrBase + j) * 132 + cl] = v;
            }
        }
        __syncthreads();
        // read back row-major: 32 rows x 128 cols, 4 passes x (256 thr x 16B)
        #pragma unroll
        for (int p = 0; p < 4; ++p) {
            const int flat = p * 1024 + t * 4;
            const int r = flat >> 7, c = flat & 127;
            const int R = rowBase + m * 16 + (r < 16 ? r : 48 + r);
            const int C = colBase + c;
            if (R < M && C < Nn) {
                float4 v4 = *reinterpret_cast<const float4*>(Es + r * 132 + c);
                if (EPI == EPI_HEADS3) {
                    *reinterpret_cast<float4*>(
                        (float*)Cout + (size_t)hh * headStride + (size_t)R * 512 + (ccBase + c)) = v4;
                } else if (OUT_BF16) {
                    ushort4 o;
                    o.x = f2bf(v4.x); o.y = f2bf(v4.y); o.z = f2bf(v4.z); o.w = f2bf(v4.w);
                    *reinterpret_cast<ushort4*>((unsigned short*)Cout + (size_t)R * Nn + C) = o;
                } else {
                    *reinterpret_cast<float4*>((float*)Cout + (size_t)R * Nn + C) = v4;
                }
            }
        }
        __syncthreads();
    }
}

// ---------------- combined CSR build (both graphs, rows 0..2N-1) ----------------
__global__ void hist2_kernel(const int* __restrict__ edst0, const int* __restrict__ edst1,
                             int* __restrict__ deg, int e, int nHalf) {
    int i = blockIdx.x * blockDim.x + threadIdx.x;
    if (i < 2 * e) {
        int d = (i < e) ? edst0[i] : (edst1[i - e] + nHalf);
        atomicAdd(&deg[d], 1);
    }
}

__global__ __launch_bounds__(1024) void scan_block_kernel(const int* __restrict__ deg,
                                                          int* __restrict__ excl,
                                                          int* __restrict__ bsum, int n) {
    __shared__ int buf[1024];
    int i = blockIdx.x * 1024 + (int)threadIdx.x;
    int v = (i < n) ? deg[i] : 0;
    buf[threadIdx.x] = v;
    __syncthreads();
    for (int off = 1; off < 1024; off <<= 1) {
        int tv = (threadIdx.x >= (unsigned)off) ? buf[threadIdx.x - off] : 0;
        __syncthreads();
        buf[threadIdx.x] += tv;
        __syncthreads();
    }
    if (i < n) excl[i] = buf[threadIdx.x] - v;
    if (threadIdx.x == 1023) bsum[blockIdx.x] = buf[1023];
}

__global__ __launch_bounds__(1024) void scan_tops_kernel(int* __restrict__ bsum, int nb) {
    __shared__ int buf[1024];
    int v = ((int)threadIdx.x < nb) ? bsum[threadIdx.x] : 0;
    buf[threadIdx.x] = v;
    __syncthreads();
    for (int off = 1; off < 1024; off <<= 1) {
        int tv = (threadIdx.x >= (unsigned)off) ? buf[threadIdx.x - off] : 0;
        __syncthreads();
        buf[threadIdx.x] += tv;
        __syncthreads();
    }
    if ((int)threadIdx.x < nb) bsum[threadIdx.x] = buf[threadIdx.x] - v;
}

__global__ void scan_add_kernel(int* __restrict__ row_start, const int* __restrict__ bsum,
                                const int* __restrict__ deg, int* __restrict__ cursor, int n) {
    int i = blockIdx.x * blockDim.x + threadIdx.x;
    if (i < n) {
        int s = row_start[i] + bsum[i >> 10];
        row_start[i] = s;
        cursor[i] = s;
        if (i == n - 1) row_start[n] = s + deg[i];
    }
}

// ---- windowed XCD-local scatter ----
#define SC_EPT 8
__global__ __launch_bounds__(256) void scatter_win_kernel(
    const int* __restrict__ sadj, const int* __restrict__ fadj,
    int* __restrict__ cursor, int* __restrict__ csr_src,
    int e, int nHalf, int winSize)
{
    const int win = blockIdx.x & 7;
    const int chunk = blockIdx.x >> 3;
    const int lo = win * winSize, hi = lo + winSize;
    const int base = chunk * (256 * SC_EPT);
    const int e2 = 2 * e;
    #pragma unroll
    for (int r = 0; r < SC_EPT; ++r) {
        int i = base + r * 256 + (int)threadIdx.x;
        if (i >= e2) break;
        int src, d;
        if (i < e) { src = sadj[i];     d = sadj[e + i]; }
        else       { int j = i - e; src = fadj[j]; d = fadj[e + j] + nHalf; }
        if (d >= lo && d < hi) {
            int pos = atomicAdd(&cursor[d], 1);
            csr_src[pos] = src;
        }
    }
}

// ---------------- gather aggregation (bf16 rows, fp32 accum) ----------------
template<int F, bool SRC_OFFSET>
__global__ __launch_bounds__(256) void agg_combine_kernel(
    const unsigned short* __restrict__ xin, const int* __restrict__ row_start,
    const int* __restrict__ csr_src, const float* __restrict__ bias,
    unsigned short* __restrict__ out, int n2, int nHalf)
{
    constexpr int LPN = F / 8;                 // lanes per node, 8 bf16 (16B) each
    int node = blockIdx.x * (256 / LPN) + (int)threadIdx.x / LPN;
    int lane = (int)threadIdx.x % LPN;
    if (node >= n2) return;
    const int srcAdd  = (SRC_OFFSET && node >= nHalf) ? nHalf : 0;
    const int selfIdx = SRC_OFFSET ? node : (node >= nHalf ? node - nHalf : node);
    int beg = row_start[node], end = row_start[node + 1];
    float a[8];
    #pragma unroll
    for (int j = 0; j < 8; ++j) a[j] = 0.f;
    int e = beg;
    for (; e + 4 <= end; e += 4) {
        int s0 = csr_src[e] + srcAdd, s1 = csr_src[e+1] + srcAdd;
        int s2 = csr_src[e+2] + srcAdd, s3 = csr_src[e+3] + srcAdd;
        ushort8v v0 = *reinterpret_cast<const ushort8v*>(xin + (size_t)s0 * F + lane * 8);
        ushort8v v1 = *reinterpret_cast<const ushort8v*>(xin + (size_t)s1 * F + lane * 8);
        ushort8v v2 = *reinterpret_cast<const ushort8v*>(xin + (size_t)s2 * F + lane * 8);
        ushort8v v3 = *reinterpret_cast<const ushort8v*>(xin + (size_t)s3 * F + lane * 8);
        #pragma unroll
        for (int j = 0; j < 8; ++j)
            a[j] += bf2f(v0[j]) + bf2f(v1[j]) + bf2f(v2[j]) + bf2f(v3[j]);
    }
    for (; e < end; ++e) {
        int s = csr_src[e] + srcAdd;
        ushort8v v = *reinterpret_cast<const ushort8v*>(xin + (size_t)s * F + lane * 8);
        #pragma unroll
        for (int j = 0; j < 8; ++j) a[j] += bf2f(v[j]);
    }
    ushort8v sv = *reinterpret_cast<const ushort8v*>(xin + (size_t)selfIdx * F + lane * 8);
    ushort8v o;
    #pragma unroll
    for (int j = 0; j < 8; ++j)
        o[j] = f2bf(fmaxf(bf2f(sv[j]) + a[j] + bias[lane * 8 + j], 0.f));
    *reinterpret_cast<ushort8v*>(out + (size_t)node * F + lane * 8) = o;
}

// ---------------- fused spatial attention + mlp (16 nodes/block) ----------------
__global__ __launch_bounds__(256) void attn_mlp_kernel(
    const float* __restrict__ emb1, const float* __restrict__ emb2,
    const float* __restrict__ Wa1, const float* __restrict__ ba1,
    const float* __restrict__ Wa2, const float* __restrict__ Wmlp,
    const float* __restrict__ bmlp, float* __restrict__ out,
    unsigned short* __restrict__ out_bf, int n)
{
    __shared__ float sWa1[NHID2][ATTH];
    __shared__ float sba1[ATTH], sWa2[ATTH];
    __shared__ float sWmlp[NHID2][NHID2 + 1];
    __shared__ float sbmlp[NHID2];
    __shared__ float zs[4][3][NHID2 + 1];
    __shared__ float part[4][3][ATTH];
    __shared__ float sbeta[4][3];
    __shared__ float es[4][NHID2 + 1];

    int t = threadIdx.x;
    for (int idx = t; idx < NHID2 * ATTH; idx += 256) sWa1[idx / ATTH][idx % ATTH] = Wa1[idx];
    if (t < ATTH) { sba1[t] = ba1[t]; sWa2[t] = Wa2[t]; }
    for (int idx = t; idx < NHID2 * NHID2; idx += 256) sWmlp[idx / NHID2][idx % NHID2] = Wmlp[idx];
    if (t < NHID2) sbmlp[t] = bmlp[t];

    int w = t >> 6, lane = t & 63;

    for (int rep = 0; rep < 4; ++rep) {
        int node = blockIdx.x * 16 + rep * 4 + w;
        float z0 = 0.f, z2 = 0.f;
        if (node < n) {
            z0 = emb1[(size_t)node * NHID2 + lane];
            z2 = emb2[(size_t)node * NHID2 + lane];
        }
        zs[w][0][lane] = z0;
        zs[w][1][lane] = 0.5f * (z0 + z2);
        zs[w][2][lane] = z2;
        __syncthreads();

        if (t < 192) {
            int ww = t / 48, k = (t / 16) % 3, h = t % 16;
            float p = 0.f;
            #pragma unroll 8
            for (int i = 0; i < NHID2; ++i) p += zs[ww][k][i] * sWa1[i][h];
            part[ww][k][h] = tanhf(p + sba1[h]) * sWa2[h];
        }
        __syncthreads();
        if (t < 12) {
            int ww = t / 3, k = t % 3;
            float s = 0.f;
            #pragma unroll
            for (int h = 0; h < ATTH; ++h) s += part[ww][k][h];
            part[ww][k][0] = s;
        }
        __syncthreads();
        if (t < 4) {
            float w0 = part[t][0][0], w1 = part[t][1][0], w2 = part[t][2][0];
            float m = fmaxf(w0, fmaxf(w1, w2));
            float e0 = expf(w0 - m), e1 = expf(w1 - m), e2 = expf(w2 - m);
            float d = e0 + e1 + e2;
            sbeta[t][0] = e0 / d; sbeta[t][1] = e1 / d; sbeta[t][2] = e2 / d;
        }
        __syncthreads();
        es[w][lane] = sbeta[w][0] * zs[w][0][lane] + sbeta[w][1] * zs[w][1][lane]
                    + sbeta[w][2] * zs[w][2][lane];
        __syncthreads();
        if (node < n) {
            float v = sbmlp[lane];
            #pragma unroll 8
            for (int i = 0; i < NHID2; ++i) v = fmaf(es[w][i], sWmlp[i][lane], v);
            out[(size_t)node * NHID2 + lane] = v;
            out_bf[(size_t)node * NHID2 + lane] = f2bf(v);
        }
        __syncthreads();
    }
}

// ---------------- launcher ----------------
extern "C" void kernel_launch(void* const* d_in, const int* in_sizes, int n_in,
                              void* d_out, int out_size, void* d_ws, size_t ws_size,
                              hipStream_t stream) {
    const float* x    = (const float*)d_in[0];
    const int*   sadj = (const int*)d_in[1];
    const int*   fadj = (const int*)d_in[2];
    const int N = in_sizes[0] / NFEAT;
    const int E = in_sizes[1] / 2;
    const int N2 = 2 * N;
    const float* Wg1a = (const float*)d_in[3];
    const float* bg1a = (const float*)d_in[4];
    const float* Wg1b = (const float*)d_in[5];
    const float* bg1b = (const float*)d_in[6];
    const float* Wg2a = (const float*)d_in[7];
    const float* bg2a = (const float*)d_in[8];
    const float* Wg2b = (const float*)d_in[9];
    const float* bg2b = (const float*)d_in[10];
    const float* Wa1  = (const float*)d_in[11];
    const float* ba1  = (const float*)d_in[12];
    const float* Wa2  = (const float*)d_in[13];
    const float* Wmlp = (const float*)d_in[14];
    const float* bmlp = (const float*)d_in[15];
    const float* Wd   = (const float*)d_in[16];
    const float* bd   = (const float*)d_in[17];
    const float* bn_g = (const float*)d_in[18];
    const float* bn_b = (const float*)d_in[19];
    const float* bn_m = (const float*)d_in[20];
    const float* bn_v = (const float*)d_in[21];
    const float* Wpi  = (const float*)d_in[22];
    const float* bpi  = (const float*)d_in[23];
    const float* Wv   = (const float*)d_in[24];
    const float* bv   = (const float*)d_in[25];
    const float* Wmu  = (const float*)d_in[26];
    const float* bmu  = (const float*)d_in[27];

    float* out   = (float*)d_out;
    float* emb1  = out;                              // [N,64] (emb2 follows)
    float* embO  = out + 2 * (size_t)N * NHID2;      // [N,64]
    float* pi    = out + 3 * (size_t)N * NHID2;      // [N,512]
    float* var_  = pi + (size_t)N * NFEAT;           // [N,512]
    float* mean_ = var_ + (size_t)N * NFEAT;         // [N,512]

    // ---- workspace carve (256B aligned) ----
    char* wsb = (char*)d_ws;
    auto alloc = [&](size_t bytes) { char* p = wsb; wsb += (bytes + 255) & ~(size_t)255; return p; };
    unsigned short* xw_bf   = (unsigned short*)alloc((size_t)N  * NHID1 * 2);
    unsigned short* hw_bf   = (unsigned short*)alloc((size_t)N2 * NHID2 * 2);
    unsigned short* h3_bf   = (unsigned short*)alloc((size_t)N2 * NHID2 * 2);
    unsigned short* embO_bf = (unsigned short*)alloc((size_t)N  * NHID2 * 2);
    unsigned short* hdec_bf = (unsigned short*)alloc((size_t)N  * NHID1 * 2);
    unsigned short* Wg1a_t  = (unsigned short*)alloc((size_t)NFEAT * NHID1 * 2);
    unsigned short* Wg1b_t  = (unsigned short*)alloc((size_t)NHID1 * NHID1 * 2);
    unsigned short* Wg2a_t  = (unsigned short*)alloc((size_t)NHID1 * NHID2 * 2);
    unsigned short* Wg2b_t  = (unsigned short*)alloc((size_t)NHID2 * NHID2 * 2);
    unsigned short* Wd_t    = (unsigned short*)alloc((size_t)NHID2 * NHID1 * 2);
    unsigned short* Wcat_t  = (unsigned short*)alloc((size_t)3 * NFEAT * NHID1 * 2); // [1536][256]
    int* deg       = (int*)alloc((size_t)N2 * 4);
    int* row_start = (int*)alloc((size_t)(N2 + 1) * 4);
    int* cursor    = (int*)alloc((size_t)N2 * 4);
    int* bsum      = (int*)alloc((size_t)1024 * 4);
    int* csr_src   = (int*)alloc((size_t)2 * E * 4);

    // big transient bf16 buffers live in not-yet-written output head segments
    unsigned short* x_bf  = (unsigned short*)mean_;  // [N,512]  bf16
    unsigned short* h1_bf = (unsigned short*)pi;     // [2N,256] bf16
    unsigned short* h_bf  = (unsigned short*)var_;   // [2N,256] bf16

    const int gyN  = (N + 127) / 128;
    const int gyN2 = (N2 + 127) / 128;
    const int nb   = (N2 + 1023) / 1024;

    // ---- conversions ----
    convert_x_kernel<<<2048, 256, 0, stream>>>(x, x_bf, (long)N * NFEAT / 4);
    WPack wp;
    wp.s[0] = {Wg1a, Wg1a_t, NFEAT, NHID1};
    wp.s[1] = {Wg1b, Wg1b_t, NHID1, NHID1};
    wp.s[2] = {Wg2a, Wg2a_t, NHID1, NHID2};
    wp.s[3] = {Wg2b, Wg2b_t, NHID2, NHID2};
    wp.s[4] = {Wd,   Wd_t,   NHID2, NHID1};
    wp.s[5] = {Wpi,  Wcat_t,                          NHID1, NFEAT};
    wp.s[6] = {Wv,   Wcat_t + (size_t)NFEAT * NHID1,  NHID1, NFEAT};
    wp.s[7] = {Wmu,  Wcat_t + (size_t)2 * NFEAT * NHID1, NHID1, NFEAT};
    convert_wt_all_kernel<<<dim3(64, 8), 256, 0, stream>>>(wp);

    // ---- combined CSR build (both graphs) ----
    hipMemsetAsync(deg, 0, (size_t)N2 * sizeof(int), stream);
    hist2_kernel<<<(2 * E + 255) / 256, 256, 0, stream>>>(sadj + E, fadj + E, deg, E, N);
    scan_block_kernel<<<nb, 1024, 0, stream>>>(deg, row_start, bsum, N2);
    scan_tops_kernel<<<1, 1024, 0, stream>>>(bsum, nb);
    scan_add_kernel<<<(N2 + 255) / 256, 256, 0, stream>>>(row_start, bsum, deg, cursor, N2);
    {
        const int chunks = (2 * E + 256 * SC_EPT - 1) / (256 * SC_EPT);
        const int winSize = (N2 + 7) / 8;
        scatter_win_kernel<<<chunks * 8, 256, 0, stream>>>(
            sadj, fadj, cursor, csr_src, E, N, winSize);
    }

    // ---- GIN, both graphs batched as M = 2N ----
    // xw = x @ Wg1a
    mfma_gemm_kernel<EPI_NONE,1><<<dim3(2, gyN), 256, 0, stream>>>(
        x_bf, Wg1a_t, nullptr, xw_bf, N, NFEAT, NHID1, 0,
        nullptr, nullptr, nullptr, nullptr);
    // h1 = relu(xw_self + agg(xw) + bg1a)   [2N,256]
    agg_combine_kernel<NHID1,false><<<(N2 * (NHID1/8) + 255) / 256, 256, 0, stream>>>(
        xw_bf, row_start, csr_src, bg1a, h1_bf, N2, N);
    // h = relu(h1 @ Wg1b + bg1b)            [2N,256]
    mfma_gemm_kernel<EPI_RELU,1><<<dim3(2, gyN2), 256, 0, stream>>>(
        h1_bf, Wg1b_t, bg1b, h_bf, N2, NHID1, NHID1, 0,
        nullptr, nullptr, nullptr, nullptr);
    // hw = h @ Wg2a                         [2N,64]
    mfma_gemm_kernel<EPI_NONE,1><<<dim3(1, gyN2), 256, 0, stream>>>(
        h_bf, Wg2a_t, nullptr, hw_bf, N2, NHID1, NHID2, 0,
        nullptr, nullptr, nullptr, nullptr);
    // h3 = relu(hw_self + agg(hw) + bg2a)   [2N,64]
    agg_combine_kernel<NHID2,true><<<(N2 * (NHID2/8) + 255) / 256, 256, 0, stream>>>(
        hw_bf, row_start, csr_src, bg2a, h3_bf, N2, N);
    // emb1‖emb2 = h3 @ Wg2b + bg2b  (fp32, contiguous in d_out)
    mfma_gemm_kernel<EPI_NONE,0><<<dim3(1, gyN2), 256, 0, stream>>>(
        h3_bf, Wg2b_t, bg2b, emb1, N2, NHID2, NHID2, 0,
        nullptr, nullptr, nullptr, nullptr);

    // ---- attention + mlp -> embO (fp32) + embO_bf ----
    attn_mlp_kernel<<<(N + 15) / 16, 256, 0, stream>>>(
        emb1, emb1 + (size_t)N * NHID2, Wa1, ba1, Wa2, Wmlp, bmlp, embO, embO_bf, N);

    // ---- decoder: hdec = relu(BN(embO @ Wd + bd)) ----
    mfma_gemm_kernel<EPI_BNRELU,1><<<dim3(2, gyN), 256, 0, stream>>>(
        embO_bf, Wd_t, bd, hdec_bf, N, NHID2, NHID1, 0,
        bn_g, bn_b, bn_m, bn_v);

    // ---- fused heads: [pi | var | mean] = acts(hdec @ [Wpi|Wv|Wmu]^T + b) ----
    mfma_gemm_kernel<EPI_HEADS3,0><<<dim3(12, gyN), 256, 0, stream>>>(
        hdec_bf, Wcat_t, nullptr, pi, N, NHID1, 3 * NFEAT, (long)N * NFEAT,
        bpi, bv, bmu, nullptr);
}

// Round 9
// 865.261 us; speedup vs baseline: 1.4686x; 1.0210x over previous
//
#include <hip/hip_runtime.h>
#include <hip/hip_bf16.h>
#include <cstdint>
#include <cstddef>

#define NFEAT 512
#define NHID1 256
#define NHID2 64
#define ATTH  16

typedef __attribute__((ext_vector_type(8))) short short8v;           // 8 bf16 (4 VGPRs)
typedef __attribute__((ext_vector_type(8))) unsigned short ushort8v; // 16B load
typedef __attribute__((ext_vector_type(4))) float f32x4;             // mfma accumulator

enum { EPI_NONE=0, EPI_RELU=1, EPI_BNRELU=2, EPI_HEADS3=3 };

static __device__ __forceinline__ float bf2f(unsigned short u) {
    return __uint_as_float(((unsigned int)u) << 16);
}
static __device__ __forceinline__ unsigned short f2bf(float f) {
    __hip_bfloat16 h = __float2bfloat16(f);   // RNE
    return *reinterpret_cast<unsigned short*>(&h);
}

// ---------------- conversion kernels ----------------
__global__ __launch_bounds__(256) void convert_x_kernel(const float* __restrict__ in,
                                                        unsigned short* __restrict__ out, long n4) {
    long i = blockIdx.x * (long)blockDim.x + threadIdx.x;
    long stride = (long)gridDim.x * blockDim.x;
    for (; i < n4; i += stride) {
        float4 v = reinterpret_cast<const float4*>(in)[i];
        ushort4 o;
        o.x = f2bf(v.x); o.y = f2bf(v.y); o.z = f2bf(v.z); o.w = f2bf(v.w);
        reinterpret_cast<ushort4*>(out)[i] = o;
    }
}

struct WSpec { const float* W; unsigned short* Wt; int K, Nn; };
struct WPack { WSpec s[8]; };

// Wt[n][k] = bf16(W[k][n]) for all 8 weights in one launch; grid.y = weight id
__global__ __launch_bounds__(256) void convert_wt_all_kernel(WPack p) {
    WSpec sp = p.s[blockIdx.y];
    int total = sp.K * sp.Nn;
    for (int idx = blockIdx.x * 256 + threadIdx.x; idx < total; idx += gridDim.x * 256) {
        int n = idx / sp.K, k = idx % sp.K;
        sp.Wt[idx] = f2bf(sp.W[(size_t)k * sp.Nn + n]);
    }
}

// ---------------- bf16 MFMA GEMM: C = epi(A[M,K] @ Bt[Nn,K]^T + bias) ----------------
// 128x128 tile, 4 waves (2x2), 16x16x32 mfma, BK=32, global_load_lds width-16 staging.
// 1-D grid with XCD-aware decode: id%8 = XCD slot, id/8 enumerates (colTile fastest)
// so all CT col-tiles of a row band run on ONE XCD -> A band L2-resident.
// Epilogue: per m-quadrant LDS transpose -> vectorized full-line stores.
template<int EPI, int OUT_BF16>
__global__ __launch_bounds__(256) void mfma_gemm_kernel(
    const unsigned short* __restrict__ A, const unsigned short* __restrict__ Bt,
    const float* __restrict__ bias, void* __restrict__ Cout,
    int M, int K, int Nn, long headStride, int CT, int GY,
    const float* __restrict__ bp0, const float* __restrict__ bp1,
    const float* __restrict__ bp2, const float* __restrict__ bp3)
{
    // XCD-aware block decode
    const int id = blockIdx.x;
    const int xcd = id & 7, q = id >> 3;
    const int ct = q % CT, rq = q / CT;
    const int rb = xcd + rq * 8;
    if (rb >= GY) return;
    const int rowBase = rb * 128, colBase = ct * 128;

    __shared__ __align__(16) char smem[32 * 132 * 4];   // 16896 B (>= 16384 staging)
    unsigned short* As = (unsigned short*)smem;         // 128*32 u16 = 8 KB
    unsigned short* Bs = As + 128 * 32;                 // 8 KB
    float* Es = (float*)smem;                           // epilogue transpose buffer

    const int t = threadIdx.x;
    const int w = t >> 6, l = t & 63;
    const int wr = w >> 1, wc = w & 1;

    f32x4 acc[4][4];
    #pragma unroll
    for (int m = 0; m < 4; ++m)
        #pragma unroll
        for (int n = 0; n < 4; ++n) acc[m][n] = (f32x4){0.f, 0.f, 0.f, 0.f};

    const int c0 = w * 2, c1 = w * 2 + 1;
    const int r0 = c0 * 16 + (l >> 2), r1 = c1 * 16 + (l >> 2);
    const int kid = (l & 3) * 8;
    int ar0 = rowBase + r0; if (ar0 >= M) ar0 = M - 1;
    int ar1 = rowBase + r1; if (ar1 >= M) ar1 = M - 1;
    int br0 = colBase + r0; if (br0 >= Nn) br0 = Nn - 1;
    int br1 = colBase + r1; if (br1 >= Nn) br1 = Nn - 1;
    const unsigned short* a0p = A + (size_t)ar0 * K + kid;
    const unsigned short* a1p = A + (size_t)ar1 * K + kid;
    const unsigned short* b0p = Bt + (size_t)br0 * K + kid;
    const unsigned short* b1p = Bt + (size_t)br1 * K + kid;

    const int frow = (l & 15), fk = (l >> 4) * 8;

    for (int k0 = 0; k0 < K; k0 += 32) {
        __builtin_amdgcn_global_load_lds(
            (const __attribute__((address_space(1))) void*)(a0p + k0),
            (__attribute__((address_space(3))) void*)(As + c0 * 512), 16, 0, 0);
        __builtin_amdgcn_global_load_lds(
            (const __attribute__((address_space(1))) void*)(a1p + k0),
            (__attribute__((address_space(3))) void*)(As + c1 * 512), 16, 0, 0);
        __builtin_amdgcn_global_load_lds(
            (const __attribute__((address_space(1))) void*)(b0p + k0),
            (__attribute__((address_space(3))) void*)(Bs + c0 * 512), 16, 0, 0);
        __builtin_amdgcn_global_load_lds(
            (const __attribute__((address_space(1))) void*)(b1p + k0),
            (__attribute__((address_space(3))) void*)(Bs + c1 * 512), 16, 0, 0);
        __syncthreads();

        short8v a[4], b[4];
        #pragma unroll
        for (int m = 0; m < 4; ++m)
            a[m] = *reinterpret_cast<const short8v*>(As + (wr * 64 + m * 16 + frow) * 32 + fk);
        #pragma unroll
        for (int n = 0; n < 4; ++n)
            b[n] = *reinterpret_cast<const short8v*>(Bs + (wc * 64 + n * 16 + frow) * 32 + fk);
        #pragma unroll
        for (int m = 0; m < 4; ++m)
            #pragma unroll
            for (int n = 0; n < 4; ++n)
                acc[m][n] = __builtin_amdgcn_mfma_f32_16x16x32_bf16(a[m], b[n], acc[m][n], 0, 0, 0);
        __syncthreads();
    }

    // ---- epilogue: activation in fragment layout -> LDS -> vectorized stores ----
    const int colLoc = wc * 64 + (l & 15);        // + n*16
    const int lrBase = wr * 16 + (l >> 4) * 4;    // + j  (0..31)
    const int hh = colBase >> 9;                   // HEADS3: block-uniform head id
    const int ccBase = colBase & 511;

    #pragma unroll
    for (int m = 0; m < 4; ++m) {
        #pragma unroll
        for (int n = 0; n < 4; ++n) {
            const int cl = colLoc + n * 16;
            const int c  = colBase + cl;
            const int cs = (c < Nn) ? c : 0;      // safe index for OOB cols (Nn=64 tiles)
            float bia = 0.f, g = 0.f, bb = 0.f, mm = 0.f, iv = 0.f;
            if (EPI == EPI_HEADS3) {
                int cc = c & 511;
                bia = (hh == 0) ? bp0[cc] : (hh == 1) ? bp1[cc] : bp2[cc];
            } else {
                if (bias) bia = bias[cs];
                if (EPI == EPI_BNRELU) {
                    g = bp0[cs]; bb = bp1[cs]; mm = bp2[cs];
                    iv = rsqrtf(bp3[cs] + 1e-5f);
                }
            }
            #pragma unroll
            for (int j = 0; j < 4; ++j) {
                float v = acc[m][n][j] + bia;
                if (EPI == EPI_RELU) {
                    v = fmaxf(v, 0.f);
                } else if (EPI == EPI_BNRELU) {
                    v = (v - mm) * iv * g + bb;
                    v = fmaxf(v, 0.f);
                } else if (EPI == EPI_HEADS3) {
                    if (hh == 0) {
                        v = 1.f / (1.f + __expf(-v));
                    } else if (hh == 1) {
                        float sp = (v > 20.f) ? v : __logf(1.f + __expf(v));
                        v = fminf(fmaxf(sp, 1e-4f), 1e4f);
                    } else {
                        v = fminf(fmaxf(__expf(v), 1e-5f), 1e6f);
                    }
                }
                Es[(lrBase + j) * 132 + cl] = v;
            }
        }
        __syncthreads();
        // read back row-major: 32 rows x 128 cols, 4 passes x (256 thr x 16B)
        #pragma unroll
        for (int p = 0; p < 4; ++p) {
            const int flat = p * 1024 + t * 4;
            const int r = flat >> 7, c = flat & 127;
            const int R = rowBase + m * 16 + (r < 16 ? r : 48 + r);
            const int C = colBase + c;
            if (R < M && C < Nn) {
                float4 v4 = *reinterpret_cast<const float4*>(Es + r * 132 + c);
                if (EPI == EPI_HEADS3) {
                    *reinterpret_cast<float4*>(
                        (float*)Cout + (size_t)hh * headStride + (size_t)R * 512 + (ccBase + c)) = v4;
                } else if (OUT_BF16) {
                    ushort4 o;
                    o.x = f2bf(v4.x); o.y = f2bf(v4.y); o.z = f2bf(v4.z); o.w = f2bf(v4.w);
                    *reinterpret_cast<ushort4*>((unsigned short*)Cout + (size_t)R * Nn + C) = o;
                } else {
                    *reinterpret_cast<float4*>((float*)Cout + (size_t)R * Nn + C) = v4;
                }
            }
        }
        __syncthreads();
    }
}

// ---------------- combined CSR build (both graphs, rows 0..2N-1) ----------------
__global__ void hist2_kernel(const int* __restrict__ edst0, const int* __restrict__ edst1,
                             int* __restrict__ deg, int e, int nHalf) {
    int i = blockIdx.x * blockDim.x + threadIdx.x;
    if (i < 2 * e) {
        int d = (i < e) ? edst0[i] : (edst1[i - e] + nHalf);
        atomicAdd(&deg[d], 1);
    }
}

__global__ __launch_bounds__(1024) void scan_block_kernel(const int* __restrict__ deg,
                                                          int* __restrict__ excl,
                                                          int* __restrict__ bsum, int n) {
    __shared__ int buf[1024];
    int i = blockIdx.x * 1024 + (int)threadIdx.x;
    int v = (i < n) ? deg[i] : 0;
    buf[threadIdx.x] = v;
    __syncthreads();
    for (int off = 1; off < 1024; off <<= 1) {
        int tv = (threadIdx.x >= (unsigned)off) ? buf[threadIdx.x - off] : 0;
        __syncthreads();
        buf[threadIdx.x] += tv;
        __syncthreads();
    }
    if (i < n) excl[i] = buf[threadIdx.x] - v;
    if (threadIdx.x == 1023) bsum[blockIdx.x] = buf[1023];
}

__global__ __launch_bounds__(1024) void scan_tops_kernel(int* __restrict__ bsum, int nb) {
    __shared__ int buf[1024];
    int v = ((int)threadIdx.x < nb) ? bsum[threadIdx.x] : 0;
    buf[threadIdx.x] = v;
    __syncthreads();
    for (int off = 1; off < 1024; off <<= 1) {
        int tv = (threadIdx.x >= (unsigned)off) ? buf[threadIdx.x - off] : 0;
        __syncthreads();
        buf[threadIdx.x] += tv;
        __syncthreads();
    }
    if ((int)threadIdx.x < nb) bsum[threadIdx.x] = buf[threadIdx.x] - v;
}

__global__ void scan_add_kernel(int* __restrict__ row_start, const int* __restrict__ bsum,
                                const int* __restrict__ deg, int* __restrict__ cursor, int n) {
    int i = blockIdx.x * blockDim.x + threadIdx.x;
    if (i < n) {
        int s = row_start[i] + bsum[i >> 10];
        row_start[i] = s;
        cursor[i] = s;
        if (i == n - 1) row_start[n] = s + deg[i];
    }
}

// ---- windowed XCD-local scatter ----
#define SC_EPT 8
__global__ __launch_bounds__(256) void scatter_win_kernel(
    const int* __restrict__ sadj, const int* __restrict__ fadj,
    int* __restrict__ cursor, int* __restrict__ csr_src,
    int e, int nHalf, int winSize)
{
    const int win = blockIdx.x & 7;
    const int chunk = blockIdx.x >> 3;
    const int lo = win * winSize, hi = lo + winSize;
    const int base = chunk * (256 * SC_EPT);
    const int e2 = 2 * e;
    #pragma unroll
    for (int r = 0; r < SC_EPT; ++r) {
        int i = base + r * 256 + (int)threadIdx.x;
        if (i >= e2) break;
        int src, d;
        if (i < e) { src = sadj[i];     d = sadj[e + i]; }
        else       { int j = i - e; src = fadj[j]; d = fadj[e + j] + nHalf; }
        if (d >= lo && d < hi) {
            int pos = atomicAdd(&cursor[d], 1);
            csr_src[pos] = src;
        }
    }
}

// ---------------- gather aggregation (bf16 rows, fp32 accum, 8-deep MLP) ----------------
// Accumulation is one left-associated chain per feature -> bit-identical to the
// 4-deep version (same edge order), just more loads in flight.
template<int F, bool SRC_OFFSET>
__global__ __launch_bounds__(256) void agg_combine_kernel(
    const unsigned short* __restrict__ xin, const int* __restrict__ row_start,
    const int* __restrict__ csr_src, const float* __restrict__ bias,
    unsigned short* __restrict__ out, int n2, int nHalf)
{
    constexpr int LPN = F / 8;                 // lanes per node, 8 bf16 (16B) each
    int node = blockIdx.x * (256 / LPN) + (int)threadIdx.x / LPN;
    int lane = (int)threadIdx.x % LPN;
    if (node >= n2) return;
    const int srcAdd  = (SRC_OFFSET && node >= nHalf) ? nHalf : 0;
    const int selfIdx = SRC_OFFSET ? node : (node >= nHalf ? node - nHalf : node);
    int beg = row_start[node], end = row_start[node + 1];
    float a[8];
    #pragma unroll
    for (int j = 0; j < 8; ++j) a[j] = 0.f;
    int e = beg;
    for (; e + 8 <= end; e += 8) {
        int s0 = csr_src[e]   + srcAdd, s1 = csr_src[e+1] + srcAdd;
        int s2 = csr_src[e+2] + srcAdd, s3 = csr_src[e+3] + srcAdd;
        int s4 = csr_src[e+4] + srcAdd, s5 = csr_src[e+5] + srcAdd;
        int s6 = csr_src[e+6] + srcAdd, s7 = csr_src[e+7] + srcAdd;
        ushort8v v0 = *reinterpret_cast<const ushort8v*>(xin + (size_t)s0 * F + lane * 8);
        ushort8v v1 = *reinterpret_cast<const ushort8v*>(xin + (size_t)s1 * F + lane * 8);
        ushort8v v2 = *reinterpret_cast<const ushort8v*>(xin + (size_t)s2 * F + lane * 8);
        ushort8v v3 = *reinterpret_cast<const ushort8v*>(xin + (size_t)s3 * F + lane * 8);
        ushort8v v4 = *reinterpret_cast<const ushort8v*>(xin + (size_t)s4 * F + lane * 8);
        ushort8v v5 = *reinterpret_cast<const ushort8v*>(xin + (size_t)s5 * F + lane * 8);
        ushort8v v6 = *reinterpret_cast<const ushort8v*>(xin + (size_t)s6 * F + lane * 8);
        ushort8v v7 = *reinterpret_cast<const ushort8v*>(xin + (size_t)s7 * F + lane * 8);
        #pragma unroll
        for (int j = 0; j < 8; ++j)
            a[j] += bf2f(v0[j]) + bf2f(v1[j]) + bf2f(v2[j]) + bf2f(v3[j])
                  + bf2f(v4[j]) + bf2f(v5[j]) + bf2f(v6[j]) + bf2f(v7[j]);
    }
    for (; e + 4 <= end; e += 4) {
        int s0 = csr_src[e] + srcAdd, s1 = csr_src[e+1] + srcAdd;
        int s2 = csr_src[e+2] + srcAdd, s3 = csr_src[e+3] + srcAdd;
        ushort8v v0 = *reinterpret_cast<const ushort8v*>(xin + (size_t)s0 * F + lane * 8);
        ushort8v v1 = *reinterpret_cast<const ushort8v*>(xin + (size_t)s1 * F + lane * 8);
        ushort8v v2 = *reinterpret_cast<const ushort8v*>(xin + (size_t)s2 * F + lane * 8);
        ushort8v v3 = *reinterpret_cast<const ushort8v*>(xin + (size_t)s3 * F + lane * 8);
        #pragma unroll
        for (int j = 0; j < 8; ++j)
            a[j] += bf2f(v0[j]) + bf2f(v1[j]) + bf2f(v2[j]) + bf2f(v3[j]);
    }
    for (; e < end; ++e) {
        int s = csr_src[e] + srcAdd;
        ushort8v v = *reinterpret_cast<const ushort8v*>(xin + (size_t)s * F + lane * 8);
        #pragma unroll
        for (int j = 0; j < 8; ++j) a[j] += bf2f(v[j]);
    }
    ushort8v sv = *reinterpret_cast<const ushort8v*>(xin + (size_t)selfIdx * F + lane * 8);
    ushort8v o;
    #pragma unroll
    for (int j = 0; j < 8; ++j)
        o[j] = f2bf(fmaxf(bf2f(sv[j]) + a[j] + bias[lane * 8 + j], 0.f));
    *reinterpret_cast<ushort8v*>(out + (size_t)node * F + lane * 8) = o;
}

// ---------------- fused spatial attention + mlp (16 nodes/block) ----------------
__global__ __launch_bounds__(256) void attn_mlp_kernel(
    const float* __restrict__ emb1, const float* __restrict__ emb2,
    const float* __restrict__ Wa1, const float* __restrict__ ba1,
    const float* __restrict__ Wa2, const float* __restrict__ Wmlp,
    const float* __restrict__ bmlp, float* __restrict__ out,
    unsigned short* __restrict__ out_bf, int n)
{
    __shared__ float sWa1[NHID2][ATTH];
    __shared__ float sba1[ATTH], sWa2[ATTH];
    __shared__ float sWmlp[NHID2][NHID2 + 1];
    __shared__ float sbmlp[NHID2];
    __shared__ float zs[4][3][NHID2 + 1];
    __shared__ float part[4][3][ATTH];
    __shared__ float sbeta[4][3];
    __shared__ float es[4][NHID2 + 1];

    int t = threadIdx.x;
    for (int idx = t; idx < NHID2 * ATTH; idx += 256) sWa1[idx / ATTH][idx % ATTH] = Wa1[idx];
    if (t < ATTH) { sba1[t] = ba1[t]; sWa2[t] = Wa2[t]; }
    for (int idx = t; idx < NHID2 * NHID2; idx += 256) sWmlp[idx / NHID2][idx % NHID2] = Wmlp[idx];
    if (t < NHID2) sbmlp[t] = bmlp[t];

    int w = t >> 6, lane = t & 63;

    for (int rep = 0; rep < 4; ++rep) {
        int node = blockIdx.x * 16 + rep * 4 + w;
        float z0 = 0.f, z2 = 0.f;
        if (node < n) {
            z0 = emb1[(size_t)node * NHID2 + lane];
            z2 = emb2[(size_t)node * NHID2 + lane];
        }
        zs[w][0][lane] = z0;
        zs[w][1][lane] = 0.5f * (z0 + z2);
        zs[w][2][lane] = z2;
        __syncthreads();

        if (t < 192) {
            int ww = t / 48, k = (t / 16) % 3, h = t % 16;
            float p = 0.f;
            #pragma unroll 8
            for (int i = 0; i < NHID2; ++i) p += zs[ww][k][i] * sWa1[i][h];
            part[ww][k][h] = tanhf(p + sba1[h]) * sWa2[h];
        }
        __syncthreads();
        if (t < 12) {
            int ww = t / 3, k = t % 3;
            float s = 0.f;
            #pragma unroll
            for (int h = 0; h < ATTH; ++h) s += part[ww][k][h];
            part[ww][k][0] = s;
        }
        __syncthreads();
        if (t < 4) {
            float w0 = part[t][0][0], w1 = part[t][1][0], w2 = part[t][2][0];
            float m = fmaxf(w0, fmaxf(w1, w2));
            float e0 = expf(w0 - m), e1 = expf(w1 - m), e2 = expf(w2 - m);
            float d = e0 + e1 + e2;
            sbeta[t][0] = e0 / d; sbeta[t][1] = e1 / d; sbeta[t][2] = e2 / d;
        }
        __syncthreads();
        es[w][lane] = sbeta[w][0] * zs[w][0][lane] + sbeta[w][1] * zs[w][1][lane]
                    + sbeta[w][2] * zs[w][2][lane];
        __syncthreads();
        if (node < n) {
            float v = sbmlp[lane];
            #pragma unroll 8
            for (int i = 0; i < NHID2; ++i) v = fmaf(es[w][i], sWmlp[i][lane], v);
            out[(size_t)node * NHID2 + lane] = v;
            out_bf[(size_t)node * NHID2 + lane] = f2bf(v);
        }
        __syncthreads();
    }
}

// ---------------- launcher ----------------
static inline int swz_grid(int CT, int GY) { return 8 * CT * ((GY + 7) / 8); }

extern "C" void kernel_launch(void* const* d_in, const int* in_sizes, int n_in,
                              void* d_out, int out_size, void* d_ws, size_t ws_size,
                              hipStream_t stream) {
    const float* x    = (const float*)d_in[0];
    const int*   sadj = (const int*)d_in[1];
    const int*   fadj = (const int*)d_in[2];
    const int N = in_sizes[0] / NFEAT;
    const int E = in_sizes[1] / 2;
    const int N2 = 2 * N;
    const float* Wg1a = (const float*)d_in[3];
    const float* bg1a = (const float*)d_in[4];
    const float* Wg1b = (const float*)d_in[5];
    const float* bg1b = (const float*)d_in[6];
    const float* Wg2a = (const float*)d_in[7];
    const float* bg2a = (const float*)d_in[8];
    const float* Wg2b = (const float*)d_in[9];
    const float* bg2b = (const float*)d_in[10];
    const float* Wa1  = (const float*)d_in[11];
    const float* ba1  = (const float*)d_in[12];
    const float* Wa2  = (const float*)d_in[13];
    const float* Wmlp = (const float*)d_in[14];
    const float* bmlp = (const float*)d_in[15];
    const float* Wd   = (const float*)d_in[16];
    const float* bd   = (const float*)d_in[17];
    const float* bn_g = (const float*)d_in[18];
    const float* bn_b = (const float*)d_in[19];
    const float* bn_m = (const float*)d_in[20];
    const float* bn_v = (const float*)d_in[21];
    const float* Wpi  = (const float*)d_in[22];
    const float* bpi  = (const float*)d_in[23];
    const float* Wv   = (const float*)d_in[24];
    const float* bv   = (const float*)d_in[25];
    const float* Wmu  = (const float*)d_in[26];
    const float* bmu  = (const float*)d_in[27];

    float* out   = (float*)d_out;
    float* emb1  = out;                              // [N,64] (emb2 follows)
    float* embO  = out + 2 * (size_t)N * NHID2;      // [N,64]
    float* pi    = out + 3 * (size_t)N * NHID2;      // [N,512]
    float* var_  = pi + (size_t)N * NFEAT;           // [N,512]
    float* mean_ = var_ + (size_t)N * NFEAT;         // [N,512]

    // ---- workspace carve (256B aligned) ----
    char* wsb = (char*)d_ws;
    auto alloc = [&](size_t bytes) { char* p = wsb; wsb += (bytes + 255) & ~(size_t)255; return p; };
    unsigned short* xw_bf   = (unsigned short*)alloc((size_t)N  * NHID1 * 2);
    unsigned short* hw_bf   = (unsigned short*)alloc((size_t)N2 * NHID2 * 2);
    unsigned short* h3_bf   = (unsigned short*)alloc((size_t)N2 * NHID2 * 2);
    unsigned short* embO_bf = (unsigned short*)alloc((size_t)N  * NHID2 * 2);
    unsigned short* hdec_bf = (unsigned short*)alloc((size_t)N  * NHID1 * 2);
    unsigned short* Wg1a_t  = (unsigned short*)alloc((size_t)NFEAT * NHID1 * 2);
    unsigned short* Wg1b_t  = (unsigned short*)alloc((size_t)NHID1 * NHID1 * 2);
    unsigned short* Wg2a_t  = (unsigned short*)alloc((size_t)NHID1 * NHID2 * 2);
    unsigned short* Wg2b_t  = (unsigned short*)alloc((size_t)NHID2 * NHID2 * 2);
    unsigned short* Wd_t    = (unsigned short*)alloc((size_t)NHID2 * NHID1 * 2);
    unsigned short* Wcat_t  = (unsigned short*)alloc((size_t)3 * NFEAT * NHID1 * 2); // [1536][256]
    int* deg       = (int*)alloc((size_t)N2 * 4);
    int* row_start = (int*)alloc((size_t)(N2 + 1) * 4);
    int* cursor    = (int*)alloc((size_t)N2 * 4);
    int* bsum      = (int*)alloc((size_t)1024 * 4);
    int* csr_src   = (int*)alloc((size_t)2 * E * 4);

    // big transient bf16 buffers live in not-yet-written output head segments
    unsigned short* x_bf  = (unsigned short*)mean_;  // [N,512]  bf16
    unsigned short* h1_bf = (unsigned short*)pi;     // [2N,256] bf16
    unsigned short* h_bf  = (unsigned short*)var_;   // [2N,256] bf16

    const int gyN  = (N + 127) / 128;
    const int gyN2 = (N2 + 127) / 128;
    const int nb   = (N2 + 1023) / 1024;

    // ---- conversions ----
    convert_x_kernel<<<2048, 256, 0, stream>>>(x, x_bf, (long)N * NFEAT / 4);
    WPack wp;
    wp.s[0] = {Wg1a, Wg1a_t, NFEAT, NHID1};
    wp.s[1] = {Wg1b, Wg1b_t, NHID1, NHID1};
    wp.s[2] = {Wg2a, Wg2a_t, NHID1, NHID2};
    wp.s[3] = {Wg2b, Wg2b_t, NHID2, NHID2};
    wp.s[4] = {Wd,   Wd_t,   NHID2, NHID1};
    wp.s[5] = {Wpi,  Wcat_t,                          NHID1, NFEAT};
    wp.s[6] = {Wv,   Wcat_t + (size_t)NFEAT * NHID1,  NHID1, NFEAT};
    wp.s[7] = {Wmu,  Wcat_t + (size_t)2 * NFEAT * NHID1, NHID1, NFEAT};
    convert_wt_all_kernel<<<dim3(64, 8), 256, 0, stream>>>(wp);

    // ---- combined CSR build (both graphs) ----
    hipMemsetAsync(deg, 0, (size_t)N2 * sizeof(int), stream);
    hist2_kernel<<<(2 * E + 255) / 256, 256, 0, stream>>>(sadj + E, fadj + E, deg, E, N);
    scan_block_kernel<<<nb, 1024, 0, stream>>>(deg, row_start, bsum, N2);
    scan_tops_kernel<<<1, 1024, 0, stream>>>(bsum, nb);
    scan_add_kernel<<<(N2 + 255) / 256, 256, 0, stream>>>(row_start, bsum, deg, cursor, N2);
    {
        const int chunks = (2 * E + 256 * SC_EPT - 1) / (256 * SC_EPT);
        const int winSize = (N2 + 7) / 8;
        scatter_win_kernel<<<chunks * 8, 256, 0, stream>>>(
            sadj, fadj, cursor, csr_src, E, N, winSize);
    }

    // ---- GIN, both graphs batched as M = 2N ----
    // xw = x @ Wg1a
    mfma_gemm_kernel<EPI_NONE,1><<<swz_grid(2, gyN), 256, 0, stream>>>(
        x_bf, Wg1a_t, nullptr, xw_bf, N, NFEAT, NHID1, 0, 2, gyN,
        nullptr, nullptr, nullptr, nullptr);
    // h1 = relu(xw_self + agg(xw) + bg1a)   [2N,256]
    agg_combine_kernel<NHID1,false><<<(N2 * (NHID1/8) + 255) / 256, 256, 0, stream>>>(
        xw_bf, row_start, csr_src, bg1a, h1_bf, N2, N);
    // h = relu(h1 @ Wg1b + bg1b)            [2N,256]
    mfma_gemm_kernel<EPI_RELU,1><<<swz_grid(2, gyN2), 256, 0, stream>>>(
        h1_bf, Wg1b_t, bg1b, h_bf, N2, NHID1, NHID1, 0, 2, gyN2,
        nullptr, nullptr, nullptr, nullptr);
    // hw = h @ Wg2a                         [2N,64]
    mfma_gemm_kernel<EPI_NONE,1><<<swz_grid(1, gyN2), 256, 0, stream>>>(
        h_bf, Wg2a_t, nullptr, hw_bf, N2, NHID1, NHID2, 0, 1, gyN2,
        nullptr, nullptr, nullptr, nullptr);
    // h3 = relu(hw_self + agg(hw) + bg2a)   [2N,64]
    agg_combine_kernel<NHID2,true><<<(N2 * (NHID2/8) + 255) / 256, 256, 0, stream>>>(
        hw_bf, row_start, csr_src, bg2a, h3_bf, N2, N);
    // emb1‖emb2 = h3 @ Wg2b + bg2b  (fp32, contiguous in d_out)
    mfma_gemm_kernel<EPI_NONE,0><<<swz_grid(1, gyN2), 256, 0, stream>>>(
        h3_bf, Wg2b_t, bg2b, emb1, N2, NHID2, NHID2, 0, 1, gyN2,
        nullptr, nullptr, nullptr, nullptr);

    // ---- attention + mlp -> embO (fp32) + embO_bf ----
    attn_mlp_kernel<<<(N + 15) / 16, 256, 0, stream>>>(
        emb1, emb1 + (size_t)N * NHID2, Wa1, ba1, Wa2, Wmlp, bmlp, embO, embO_bf, N);

    // ---- decoder: hdec = relu(BN(embO @ Wd + bd)) ----
    mfma_gemm_kernel<EPI_BNRELU,1><<<swz_grid(2, gyN), 256, 0, stream>>>(
        embO_bf, Wd_t, bd, hdec_bf, N, NHID2, NHID1, 0, 2, gyN,
        bn_g, bn_b, bn_m, bn_v);

    // ---- fused heads: [pi | var | mean] = acts(hdec @ [Wpi|Wv|Wmu]^T + b) ----
    mfma_gemm_kernel<EPI_HEADS3,0><<<swz_grid(12, gyN), 256, 0, stream>>>(
        hdec_bf, Wcat_t, nullptr, pi, N, NHID1, 3 * NFEAT, (long)N * NFEAT, 12, gyN,
        bpi, bv, bmu, nullptr);
}